// Round 1
// baseline (1082.592 us; speedup 1.0000x reference)
//
#include <hip/hip_runtime.h>

// ---------------------------------------------------------------------------
// VAERNN forward posterior, MI355X bf16-MFMA implementation.
// L=256 B=512 K=128 IN=64 STATE=128 OBS=128, LB = L*B = 131072 rows.
// ---------------------------------------------------------------------------

typedef __attribute__((ext_vector_type(8))) short bf16x8;
typedef __attribute__((ext_vector_type(4))) short bf16x4;
typedef __attribute__((ext_vector_type(4))) float f32x4;

#define LB 131072

__device__ __forceinline__ short f2b(float f) {
  union { float f; unsigned u; } v; v.f = f;
  unsigned r = (v.u + 0x7FFFu + ((v.u >> 16) & 1u)) >> 16;  // RNE
  return (short)r;
}
__device__ __forceinline__ float sigm(float x) { return 1.f / (1.f + __expf(-x)); }
__device__ __forceinline__ float tanh_fast(float x) { return 1.f - 2.f / (1.f + __expf(2.f * x)); }

__device__ __forceinline__ float gru_h(float xr, float xz, float xn,
                                       float hr, float hz, float hn, float ho) {
  float r = sigm(xr + hr);
  float z = sigm(xz + hz);
  float n = tanh_fast(xn + r * hn);
  return (1.f - z) * n + z * ho;
}

// ---------------------------------------------------------------------------
// K0: convert all weight matrices fp32 -> bf16 into workspace (contiguous).
// layout (element offsets): u_w1@0(8192) u_w2@8192(16384) x_w1@24576(16384)
// x_w2@40960(16384) wih@57344(49152) whh@106496(49152) pw1@155648(65536)
// pw2@221184(65536) pwmu@286720(32768) pwls@319488(32768)  total 352256
// ---------------------------------------------------------------------------
__global__ __launch_bounds__(256) void k_cvt(
    const float* __restrict__ s0, const float* __restrict__ s1,
    const float* __restrict__ s2, const float* __restrict__ s3,
    const float* __restrict__ s4, const float* __restrict__ s5,
    const float* __restrict__ s6, const float* __restrict__ s7,
    const float* __restrict__ s8, const float* __restrict__ s9,
    short* __restrict__ dst)
{
  int i = blockIdx.x * 256 + threadIdx.x;
  if (i >= 352256) return;
  const float* src; int off;
  if      (i <   8192) { src = s0; off = i; }
  else if (i <  24576) { src = s1; off = i - 8192; }
  else if (i <  40960) { src = s2; off = i - 24576; }
  else if (i <  57344) { src = s3; off = i - 40960; }
  else if (i < 106496) { src = s4; off = i - 57344; }
  else if (i < 155648) { src = s5; off = i - 106496; }
  else if (i < 221184) { src = s6; off = i - 155648; }
  else if (i < 286720) { src = s7; off = i - 221184; }
  else if (i < 319488) { src = s8; off = i - 286720; }
  else                 { src = s9; off = i - 319488; }
  dst[i] = f2b(src[off]);
}

// ---------------------------------------------------------------------------
// K1: u-path: x(64) -> relu fc(128) -> relu fc(128) -> gates GEMM (384), all
// fused. Wave-private 32-row tile, single LDS buffer (preload A-frags before
// overwriting). Writes x_gates fp32 (with bih added) to scratch.
// ---------------------------------------------------------------------------
__global__ __launch_bounds__(256) void k_upath(
    const float* __restrict__ x, const short* __restrict__ w1, const float* __restrict__ b1,
    const short* __restrict__ w2, const float* __restrict__ b2,
    const short* __restrict__ wih, const float* __restrict__ bih,
    float* __restrict__ gates)
{
  __shared__ short buf[4][32][144];
  const int tid = threadIdx.x, w = tid >> 6, l = tid & 63;
  const int lr = l & 15, lg = l >> 4;
  const int m0 = blockIdx.x * 128 + w * 32;
  short (* __restrict__ B)[144] = buf[w];

  // stage x tile (32 rows x 64 cols) as bf16
  #pragma unroll
  for (int it = 0; it < 8; ++it) {
    int idx = (it * 64 + l) * 4;
    int row = idx >> 6, col = idx & 63;
    float4 v = *reinterpret_cast<const float4*>(x + (size_t)(m0 + row) * 64 + col);
    bf16x4 p; p[0] = f2b(v.x); p[1] = f2b(v.y); p[2] = f2b(v.z); p[3] = f2b(v.w);
    *reinterpret_cast<bf16x4*>(&B[row][col]) = p;
  }
  __syncthreads();

  f32x4 acc[2][8];

  // layer1: K=64 -> N=128
  {
    bf16x8 a[2][2];
    #pragma unroll
    for (int mt = 0; mt < 2; ++mt)
      #pragma unroll
      for (int kt = 0; kt < 2; ++kt)
        a[mt][kt] = *reinterpret_cast<const bf16x8*>(&B[mt * 16 + lr][kt * 32 + lg * 8]);
    #pragma unroll
    for (int nt = 0; nt < 8; ++nt)
      #pragma unroll
      for (int mt = 0; mt < 2; ++mt) {
        f32x4 c = {0.f, 0.f, 0.f, 0.f};
        #pragma unroll
        for (int kt = 0; kt < 2; ++kt) {
          bf16x8 bv = *reinterpret_cast<const bf16x8*>(w1 + (size_t)(nt * 16 + lr) * 64 + kt * 32 + lg * 8);
          c = __builtin_amdgcn_mfma_f32_16x16x32_bf16(a[mt][kt], bv, c, 0, 0, 0);
        }
        acc[mt][nt] = c;
      }
  }
  __syncthreads();
  #pragma unroll
  for (int nt = 0; nt < 8; ++nt) {
    float bb = b1[nt * 16 + lr];
    #pragma unroll
    for (int mt = 0; mt < 2; ++mt)
      #pragma unroll
      for (int r = 0; r < 4; ++r) {
        float v = acc[mt][nt][r] + bb;
        B[mt * 16 + lg * 4 + r][nt * 16 + lr] = f2b(v > 0.f ? v : 0.f);
      }
  }
  __syncthreads();

  // layer2: K=128 -> N=128 (u_embed)
  bf16x8 a2f[2][4];
  #pragma unroll
  for (int mt = 0; mt < 2; ++mt)
    #pragma unroll
    for (int kt = 0; kt < 4; ++kt)
      a2f[mt][kt] = *reinterpret_cast<const bf16x8*>(&B[mt * 16 + lr][kt * 32 + lg * 8]);
  #pragma unroll
  for (int nt = 0; nt < 8; ++nt)
    #pragma unroll
    for (int mt = 0; mt < 2; ++mt) {
      f32x4 c = {0.f, 0.f, 0.f, 0.f};
      #pragma unroll
      for (int kt = 0; kt < 4; ++kt) {
        bf16x8 bv = *reinterpret_cast<const bf16x8*>(w2 + (size_t)(nt * 16 + lr) * 128 + kt * 32 + lg * 8);
        c = __builtin_amdgcn_mfma_f32_16x16x32_bf16(a2f[mt][kt], bv, c, 0, 0, 0);
      }
      acc[mt][nt] = c;
    }
  __syncthreads();
  #pragma unroll
  for (int nt = 0; nt < 8; ++nt) {
    float bb = b2[nt * 16 + lr];
    #pragma unroll
    for (int mt = 0; mt < 2; ++mt)
      #pragma unroll
      for (int r = 0; r < 4; ++r) {
        float v = acc[mt][nt][r] + bb;
        B[mt * 16 + lg * 4 + r][nt * 16 + lr] = f2b(v > 0.f ? v : 0.f);
      }
  }
  __syncthreads();

  // gates: K=128 -> N=384, streamed per N-tile, written fp32 with bias
  bf16x8 ag[2][4];
  #pragma unroll
  for (int mt = 0; mt < 2; ++mt)
    #pragma unroll
    for (int kt = 0; kt < 4; ++kt)
      ag[mt][kt] = *reinterpret_cast<const bf16x8*>(&B[mt * 16 + lr][kt * 32 + lg * 8]);
  for (int nt = 0; nt < 24; ++nt) {
    float bb = bih[nt * 16 + lr];
    #pragma unroll
    for (int mt = 0; mt < 2; ++mt) {
      f32x4 c = {0.f, 0.f, 0.f, 0.f};
      #pragma unroll
      for (int kt = 0; kt < 4; ++kt) {
        bf16x8 bv = *reinterpret_cast<const bf16x8*>(wih + (size_t)(nt * 16 + lr) * 128 + kt * 32 + lg * 8);
        c = __builtin_amdgcn_mfma_f32_16x16x32_bf16(ag[mt][kt], bv, c, 0, 0, 0);
      }
      #pragma unroll
      for (int r = 0; r < 4; ++r)
        gates[(size_t)(m0 + mt * 16 + lg * 4 + r) * 384 + nt * 16 + lr] = c[r] + bb;
    }
  }
}

// ---------------------------------------------------------------------------
// K2: x-path: obs(128) -> relu fc(128) -> relu fc(128) = x_embed (output 4)
// ---------------------------------------------------------------------------
__global__ __launch_bounds__(256) void k_xpath(
    const float* __restrict__ obs, const short* __restrict__ w1, const float* __restrict__ b1,
    const short* __restrict__ w2, const float* __restrict__ b2,
    float* __restrict__ xe)
{
  __shared__ short buf[4][32][144];
  const int tid = threadIdx.x, w = tid >> 6, l = tid & 63;
  const int lr = l & 15, lg = l >> 4;
  const int m0 = blockIdx.x * 128 + w * 32;
  short (* __restrict__ B)[144] = buf[w];

  #pragma unroll
  for (int it = 0; it < 16; ++it) {
    int idx = (it * 64 + l) * 4;
    int row = idx >> 7, col = idx & 127;
    float4 v = *reinterpret_cast<const float4*>(obs + (size_t)(m0 + row) * 128 + col);
    bf16x4 p; p[0] = f2b(v.x); p[1] = f2b(v.y); p[2] = f2b(v.z); p[3] = f2b(v.w);
    *reinterpret_cast<bf16x4*>(&B[row][col]) = p;
  }
  __syncthreads();

  f32x4 acc[2][8];
  // layer1: K=128 -> N=128 (preload frags, then overwrite buffer)
  bf16x8 a1f[2][4];
  #pragma unroll
  for (int mt = 0; mt < 2; ++mt)
    #pragma unroll
    for (int kt = 0; kt < 4; ++kt)
      a1f[mt][kt] = *reinterpret_cast<const bf16x8*>(&B[mt * 16 + lr][kt * 32 + lg * 8]);
  #pragma unroll
  for (int nt = 0; nt < 8; ++nt)
    #pragma unroll
    for (int mt = 0; mt < 2; ++mt) {
      f32x4 c = {0.f, 0.f, 0.f, 0.f};
      #pragma unroll
      for (int kt = 0; kt < 4; ++kt) {
        bf16x8 bv = *reinterpret_cast<const bf16x8*>(w1 + (size_t)(nt * 16 + lr) * 128 + kt * 32 + lg * 8);
        c = __builtin_amdgcn_mfma_f32_16x16x32_bf16(a1f[mt][kt], bv, c, 0, 0, 0);
      }
      acc[mt][nt] = c;
    }
  __syncthreads();
  #pragma unroll
  for (int nt = 0; nt < 8; ++nt) {
    float bb = b1[nt * 16 + lr];
    #pragma unroll
    for (int mt = 0; mt < 2; ++mt)
      #pragma unroll
      for (int r = 0; r < 4; ++r) {
        float v = acc[mt][nt][r] + bb;
        B[mt * 16 + lg * 4 + r][nt * 16 + lr] = f2b(v > 0.f ? v : 0.f);
      }
  }
  __syncthreads();

  // layer2: K=128 -> N=128, write x_embed fp32
  bf16x8 a2f[2][4];
  #pragma unroll
  for (int mt = 0; mt < 2; ++mt)
    #pragma unroll
    for (int kt = 0; kt < 4; ++kt)
      a2f[mt][kt] = *reinterpret_cast<const bf16x8*>(&B[mt * 16 + lr][kt * 32 + lg * 8]);
  #pragma unroll
  for (int nt = 0; nt < 8; ++nt) {
    float bb = b2[nt * 16 + lr];
    #pragma unroll
    for (int mt = 0; mt < 2; ++mt) {
      f32x4 c = {0.f, 0.f, 0.f, 0.f};
      #pragma unroll
      for (int kt = 0; kt < 4; ++kt) {
        bf16x8 bv = *reinterpret_cast<const bf16x8*>(w2 + (size_t)(nt * 16 + lr) * 128 + kt * 32 + lg * 8);
        c = __builtin_amdgcn_mfma_f32_16x16x32_bf16(a2f[mt][kt], bv, c, 0, 0, 0);
      }
      #pragma unroll
      for (int r = 0; r < 4; ++r) {
        float v = c[r] + bb;
        xe[(size_t)(m0 + mt * 16 + lg * 4 + r) * 128 + nt * 16 + lr] = (v > 0.f ? v : 0.f);
      }
    }
  }
}

// ---------------------------------------------------------------------------
// K3: GRU scan. 32 blocks x 16 batch rows; whh bf16 B-frags in registers
// (wave w owns gate columns [96w, 96w+96)); h fp32 in LDS; 256 steps.
// Emits PRE-update h to h_seq (matches reference scan).
// ---------------------------------------------------------------------------
__global__ __launch_bounds__(256) void k_gru(
    const float* __restrict__ gates, const short* __restrict__ whh,
    const float* __restrict__ bhh, float* __restrict__ hseq)
{
  __shared__ float hbuf[16][132];
  __shared__ float hg[16][396];
  const int tid = threadIdx.x, w = tid >> 6, l = tid & 63;
  const int lr = l & 15, lg = l >> 4;
  const int m0 = blockIdx.x * 16;

  bf16x8 bf[6][4];
  float bb[6];
  #pragma unroll
  for (int j = 0; j < 6; ++j) {
    bb[j] = bhh[w * 96 + j * 16 + lr];
    #pragma unroll
    for (int kt = 0; kt < 4; ++kt)
      bf[j][kt] = *reinterpret_cast<const bf16x8*>(whh + (size_t)(w * 96 + j * 16 + lr) * 128 + kt * 32 + lg * 8);
  }
  for (int i = tid; i < 16 * 128; i += 256) hbuf[i >> 7][i & 127] = 0.f;
  __syncthreads();

  const int erow = tid >> 4, ec0 = (tid & 15) * 8;

  for (int t = 0; t < 256; ++t) {
    // A-frags from current h (fp32 LDS -> bf16)
    bf16x8 a[4];
    #pragma unroll
    for (int kt = 0; kt < 4; ++kt) {
      float4 v0 = *reinterpret_cast<const float4*>(&hbuf[lr][kt * 32 + lg * 8]);
      float4 v1 = *reinterpret_cast<const float4*>(&hbuf[lr][kt * 32 + lg * 8 + 4]);
      bf16x8 aa;
      aa[0] = f2b(v0.x); aa[1] = f2b(v0.y); aa[2] = f2b(v0.z); aa[3] = f2b(v0.w);
      aa[4] = f2b(v1.x); aa[5] = f2b(v1.y); aa[6] = f2b(v1.z); aa[7] = f2b(v1.w);
      a[kt] = aa;
    }
    #pragma unroll
    for (int j = 0; j < 6; ++j) {
      f32x4 c = {0.f, 0.f, 0.f, 0.f};
      #pragma unroll
      for (int kt = 0; kt < 4; ++kt)
        c = __builtin_amdgcn_mfma_f32_16x16x32_bf16(a[kt], bf[j][kt], c, 0, 0, 0);
      #pragma unroll
      for (int r = 0; r < 4; ++r)
        hg[lg * 4 + r][w * 96 + j * 16 + lr] = c[r] + bb[j];
    }
    __syncthreads();

    // elementwise gates: each thread owns 8 cols of one row
    const float* gb = gates + ((size_t)t * 512 + m0 + erow) * 384;
    float4 xr0 = *reinterpret_cast<const float4*>(gb + ec0);
    float4 xr1 = *reinterpret_cast<const float4*>(gb + ec0 + 4);
    float4 xz0 = *reinterpret_cast<const float4*>(gb + 128 + ec0);
    float4 xz1 = *reinterpret_cast<const float4*>(gb + 128 + ec0 + 4);
    float4 xn0 = *reinterpret_cast<const float4*>(gb + 256 + ec0);
    float4 xn1 = *reinterpret_cast<const float4*>(gb + 256 + ec0 + 4);
    float4 hr0 = *reinterpret_cast<const float4*>(&hg[erow][ec0]);
    float4 hr1 = *reinterpret_cast<const float4*>(&hg[erow][ec0 + 4]);
    float4 hz0 = *reinterpret_cast<const float4*>(&hg[erow][128 + ec0]);
    float4 hz1 = *reinterpret_cast<const float4*>(&hg[erow][128 + ec0 + 4]);
    float4 hn0 = *reinterpret_cast<const float4*>(&hg[erow][256 + ec0]);
    float4 hn1 = *reinterpret_cast<const float4*>(&hg[erow][256 + ec0 + 4]);
    float4 ho0 = *reinterpret_cast<const float4*>(&hbuf[erow][ec0]);
    float4 ho1 = *reinterpret_cast<const float4*>(&hbuf[erow][ec0 + 4]);

    float4 nv0, nv1;
    nv0.x = gru_h(xr0.x, xz0.x, xn0.x, hr0.x, hz0.x, hn0.x, ho0.x);
    nv0.y = gru_h(xr0.y, xz0.y, xn0.y, hr0.y, hz0.y, hn0.y, ho0.y);
    nv0.z = gru_h(xr0.z, xz0.z, xn0.z, hr0.z, hz0.z, hn0.z, ho0.z);
    nv0.w = gru_h(xr0.w, xz0.w, xn0.w, hr0.w, hz0.w, hn0.w, ho0.w);
    nv1.x = gru_h(xr1.x, xz1.x, xn1.x, hr1.x, hz1.x, hn1.x, ho1.x);
    nv1.y = gru_h(xr1.y, xz1.y, xn1.y, hr1.y, hz1.y, hn1.y, ho1.y);
    nv1.z = gru_h(xr1.z, xz1.z, xn1.z, hr1.z, hz1.z, hn1.z, ho1.z);
    nv1.w = gru_h(xr1.w, xz1.w, xn1.w, hr1.w, hz1.w, hn1.w, ho1.w);

    float* hsp = hseq + ((size_t)t * 512 + m0 + erow) * 128 + ec0;
    *reinterpret_cast<float4*>(hsp)     = ho0;   // pre-update h
    *reinterpret_cast<float4*>(hsp + 4) = ho1;
    *reinterpret_cast<float4*>(&hbuf[erow][ec0])     = nv0;
    *reinterpret_cast<float4*>(&hbuf[erow][ec0 + 4]) = nv1;
    __syncthreads();
  }
}

// ---------------------------------------------------------------------------
// K4: posterior DBlock + reparam sample. Block = 32 rows, 4 waves split N.
// ---------------------------------------------------------------------------
__global__ __launch_bounds__(256) void k_post(
    const float* __restrict__ xe, const float* __restrict__ hs, const float* __restrict__ eps,
    const short* __restrict__ pw1, const float* __restrict__ pb1,
    const short* __restrict__ pw2, const float* __restrict__ pb2,
    const short* __restrict__ pwmu, const float* __restrict__ pbmu,
    const short* __restrict__ pwls, const float* __restrict__ pbls,
    float* __restrict__ mu, float* __restrict__ ls, float* __restrict__ samp)
{
  __shared__ short bin[32][272];
  __shared__ short bt[32][272];
  const int tid = threadIdx.x, w = tid >> 6, l = tid & 63;
  const int lr = l & 15, lg = l >> 4;
  const int m0 = blockIdx.x * 32;

  // stage post_in = [x_embed | h_seq] as bf16
  #pragma unroll
  for (int it = 0; it < 8; ++it) {
    int idx = (it * 256 + tid) * 4;
    int row = idx >> 8, col = idx & 255;
    const float* src = (col < 128) ? (xe + (size_t)(m0 + row) * 128 + col)
                                   : (hs + (size_t)(m0 + row) * 128 + (col - 128));
    float4 v = *reinterpret_cast<const float4*>(src);
    bf16x4 p; p[0] = f2b(v.x); p[1] = f2b(v.y); p[2] = f2b(v.z); p[3] = f2b(v.w);
    *reinterpret_cast<bf16x4*>(&bin[row][col]) = p;
  }
  __syncthreads();

  // fc1 (relu) * sigmoid(fc2): wave w owns cols [64w, 64w+64)
  f32x4 a1[2][4], a2[2][4];
  #pragma unroll
  for (int mt = 0; mt < 2; ++mt)
    #pragma unroll
    for (int j = 0; j < 4; ++j) { a1[mt][j] = (f32x4){0.f,0.f,0.f,0.f}; a2[mt][j] = (f32x4){0.f,0.f,0.f,0.f}; }
  #pragma unroll
  for (int kt = 0; kt < 8; ++kt) {
    bf16x8 a[2];
    #pragma unroll
    for (int mt = 0; mt < 2; ++mt)
      a[mt] = *reinterpret_cast<const bf16x8*>(&bin[mt * 16 + lr][kt * 32 + lg * 8]);
    #pragma unroll
    for (int j = 0; j < 4; ++j) {
      int n = (4 * w + j) * 16 + lr;
      bf16x8 b1v = *reinterpret_cast<const bf16x8*>(pw1 + (size_t)n * 256 + kt * 32 + lg * 8);
      bf16x8 b2v = *reinterpret_cast<const bf16x8*>(pw2 + (size_t)n * 256 + kt * 32 + lg * 8);
      #pragma unroll
      for (int mt = 0; mt < 2; ++mt) {
        a1[mt][j] = __builtin_amdgcn_mfma_f32_16x16x32_bf16(a[mt], b1v, a1[mt][j], 0, 0, 0);
        a2[mt][j] = __builtin_amdgcn_mfma_f32_16x16x32_bf16(a[mt], b2v, a2[mt][j], 0, 0, 0);
      }
    }
  }
  #pragma unroll
  for (int j = 0; j < 4; ++j) {
    int n = (4 * w + j) * 16 + lr;
    float bb1 = pb1[n], bb2 = pb2[n];
    #pragma unroll
    for (int mt = 0; mt < 2; ++mt)
      #pragma unroll
      for (int r = 0; r < 4; ++r) {
        float t1 = a1[mt][j][r] + bb1; t1 = t1 > 0.f ? t1 : 0.f;
        float t2 = sigm(a2[mt][j][r] + bb2);
        bt[mt * 16 + lg * 4 + r][n] = f2b(t1 * t2);
      }
  }
  __syncthreads();

  // mu/ls: wave w owns cols [32w, 32w+32) of each
  f32x4 am[2][2], al[2][2];
  #pragma unroll
  for (int mt = 0; mt < 2; ++mt)
    #pragma unroll
    for (int j = 0; j < 2; ++j) { am[mt][j] = (f32x4){0.f,0.f,0.f,0.f}; al[mt][j] = (f32x4){0.f,0.f,0.f,0.f}; }
  #pragma unroll
  for (int kt = 0; kt < 8; ++kt) {
    bf16x8 a[2];
    #pragma unroll
    for (int mt = 0; mt < 2; ++mt)
      a[mt] = *reinterpret_cast<const bf16x8*>(&bt[mt * 16 + lr][kt * 32 + lg * 8]);
    #pragma unroll
    for (int j = 0; j < 2; ++j) {
      int n = (2 * w + j) * 16 + lr;
      bf16x8 bm = *reinterpret_cast<const bf16x8*>(pwmu + (size_t)n * 256 + kt * 32 + lg * 8);
      bf16x8 bl = *reinterpret_cast<const bf16x8*>(pwls + (size_t)n * 256 + kt * 32 + lg * 8);
      #pragma unroll
      for (int mt = 0; mt < 2; ++mt) {
        am[mt][j] = __builtin_amdgcn_mfma_f32_16x16x32_bf16(a[mt], bm, am[mt][j], 0, 0, 0);
        al[mt][j] = __builtin_amdgcn_mfma_f32_16x16x32_bf16(a[mt], bl, al[mt][j], 0, 0, 0);
      }
    }
  }
  #pragma unroll
  for (int j = 0; j < 2; ++j) {
    int col = (2 * w + j) * 16 + lr;
    float bm = pbmu[col], bl = pbls[col];
    #pragma unroll
    for (int mt = 0; mt < 2; ++mt)
      #pragma unroll
      for (int r = 0; r < 4; ++r) {
        size_t off = (size_t)(m0 + mt * 16 + lg * 4 + r) * 128 + col;
        float m_ = am[mt][j][r] + bm;
        float l_ = al[mt][j][r] + bl;
        mu[off] = m_;
        ls[off] = l_;
        samp[off] = m_ + __expf(l_) * eps[off];
      }
  }
}

// ---------------------------------------------------------------------------
extern "C" void kernel_launch(void* const* d_in, const int* in_sizes, int n_in,
                              void* d_out, int out_size, void* d_ws, size_t ws_size,
                              hipStream_t stream) {
  const float* ext   = (const float*)d_in[0];
  const float* obs   = (const float*)d_in[1];
  const float* eps   = (const float*)d_in[2];
  const float* u_w1  = (const float*)d_in[3];
  const float* u_b1  = (const float*)d_in[4];
  const float* u_w2  = (const float*)d_in[5];
  const float* u_b2  = (const float*)d_in[6];
  const float* x_w1  = (const float*)d_in[7];
  const float* x_b1  = (const float*)d_in[8];
  const float* x_w2  = (const float*)d_in[9];
  const float* x_b2  = (const float*)d_in[10];
  const float* pw1   = (const float*)d_in[11];
  const float* pb1   = (const float*)d_in[12];
  const float* pw2   = (const float*)d_in[13];
  const float* pb2   = (const float*)d_in[14];
  const float* pwmu  = (const float*)d_in[15];
  const float* pbmu  = (const float*)d_in[16];
  const float* pwls  = (const float*)d_in[17];
  const float* pbls  = (const float*)d_in[18];
  const float* g_wih = (const float*)d_in[19];
  const float* g_whh = (const float*)d_in[20];
  const float* g_bih = (const float*)d_in[21];
  const float* g_bhh = (const float*)d_in[22];

  float* out = (float*)d_out;
  float* o_mu = out;
  float* o_ls = out + 16777216;
  float* o_sp = out + 33554432;
  float* o_hs = out + 50331648;
  float* o_xe = out + 67108864;
  // x_gates scratch exactly occupies outputs 0..2 (3*L*B*128 = L*B*384 floats);
  // fully consumed by k_gru before k_post overwrites the region.
  float* gates = out;

  short* wb = (short*)d_ws;
  short* c_uw1  = wb + 0;
  short* c_uw2  = wb + 8192;
  short* c_xw1  = wb + 24576;
  short* c_xw2  = wb + 40960;
  short* c_wih  = wb + 57344;
  short* c_whh  = wb + 106496;
  short* c_pw1  = wb + 155648;
  short* c_pw2  = wb + 221184;
  short* c_pwmu = wb + 286720;
  short* c_pwls = wb + 319488;

  k_cvt<<<1376, 256, 0, stream>>>(u_w1, u_w2, x_w1, x_w2, g_wih, g_whh,
                                  pw1, pw2, pwmu, pwls, wb);
  k_upath<<<1024, 256, 0, stream>>>(ext, c_uw1, u_b1, c_uw2, u_b2, c_wih, g_bih, gates);
  k_xpath<<<1024, 256, 0, stream>>>(obs, c_xw1, x_b1, c_xw2, x_b2, o_xe);
  k_gru<<<32, 256, 0, stream>>>(gates, c_whh, g_bhh, o_hs);
  k_post<<<4096, 256, 0, stream>>>(o_xe, o_hs, eps, c_pw1, pb1, c_pw2, pb2,
                                   c_pwmu, pbmu, c_pwls, pbls, o_mu, o_ls, o_sp);
}

// Round 2
// 827.881 us; speedup vs baseline: 1.3077x; 1.3077x over previous
//
#include <hip/hip_runtime.h>

// ---------------------------------------------------------------------------
// VAERNN forward posterior, MI355X bf16-MFMA implementation.
// L=256 B=512 K=128 IN=64 STATE=128 OBS=128, LB = L*B = 131072 rows.
// ---------------------------------------------------------------------------

typedef __attribute__((ext_vector_type(8))) short bf16x8;
typedef __attribute__((ext_vector_type(4))) short bf16x4;
typedef __attribute__((ext_vector_type(4))) float f32x4;

#define LB 131072

__device__ __forceinline__ short f2b(float f) {
  union { float f; unsigned u; } v; v.f = f;
  unsigned r = (v.u + 0x7FFFu + ((v.u >> 16) & 1u)) >> 16;  // RNE
  return (short)r;
}
__device__ __forceinline__ float sigm(float x) { return 1.f / (1.f + __expf(-x)); }
__device__ __forceinline__ float tanh_fast(float x) { return 1.f - 2.f / (1.f + __expf(2.f * x)); }

// ---------------------------------------------------------------------------
// K0: convert all weight matrices fp32 -> bf16 into workspace (contiguous).
// ---------------------------------------------------------------------------
__global__ __launch_bounds__(256) void k_cvt(
    const float* __restrict__ s0, const float* __restrict__ s1,
    const float* __restrict__ s2, const float* __restrict__ s3,
    const float* __restrict__ s4, const float* __restrict__ s5,
    const float* __restrict__ s6, const float* __restrict__ s7,
    const float* __restrict__ s8, const float* __restrict__ s9,
    short* __restrict__ dst)
{
  int i = blockIdx.x * 256 + threadIdx.x;
  if (i >= 352256) return;
  const float* src; int off;
  if      (i <   8192) { src = s0; off = i; }
  else if (i <  24576) { src = s1; off = i - 8192; }
  else if (i <  40960) { src = s2; off = i - 24576; }
  else if (i <  57344) { src = s3; off = i - 40960; }
  else if (i < 106496) { src = s4; off = i - 57344; }
  else if (i < 155648) { src = s5; off = i - 106496; }
  else if (i < 221184) { src = s6; off = i - 155648; }
  else if (i < 286720) { src = s7; off = i - 221184; }
  else if (i < 319488) { src = s8; off = i - 286720; }
  else                 { src = s9; off = i - 319488; }
  dst[i] = f2b(src[off]);
}

// ---------------------------------------------------------------------------
// K1: u-path: x(64) -> relu fc(128) -> relu fc(128) -> gates GEMM (384), all
// fused. Wave-private 32-row tile, single LDS buffer (preload A-frags before
// overwriting). Writes x_gates fp32 (with bih added) to scratch.
// ---------------------------------------------------------------------------
__global__ __launch_bounds__(256) void k_upath(
    const float* __restrict__ x, const short* __restrict__ w1, const float* __restrict__ b1,
    const short* __restrict__ w2, const float* __restrict__ b2,
    const short* __restrict__ wih, const float* __restrict__ bih,
    float* __restrict__ gates)
{
  __shared__ short buf[4][32][144];
  const int tid = threadIdx.x, w = tid >> 6, l = tid & 63;
  const int lr = l & 15, lg = l >> 4;
  const int m0 = blockIdx.x * 128 + w * 32;
  short (* __restrict__ B)[144] = buf[w];

  #pragma unroll
  for (int it = 0; it < 8; ++it) {
    int idx = (it * 64 + l) * 4;
    int row = idx >> 6, col = idx & 63;
    float4 v = *reinterpret_cast<const float4*>(x + (size_t)(m0 + row) * 64 + col);
    bf16x4 p; p[0] = f2b(v.x); p[1] = f2b(v.y); p[2] = f2b(v.z); p[3] = f2b(v.w);
    *reinterpret_cast<bf16x4*>(&B[row][col]) = p;
  }
  __syncthreads();

  f32x4 acc[2][8];

  // layer1: K=64 -> N=128
  {
    bf16x8 a[2][2];
    #pragma unroll
    for (int mt = 0; mt < 2; ++mt)
      #pragma unroll
      for (int kt = 0; kt < 2; ++kt)
        a[mt][kt] = *reinterpret_cast<const bf16x8*>(&B[mt * 16 + lr][kt * 32 + lg * 8]);
    #pragma unroll
    for (int nt = 0; nt < 8; ++nt)
      #pragma unroll
      for (int mt = 0; mt < 2; ++mt) {
        f32x4 c = {0.f, 0.f, 0.f, 0.f};
        #pragma unroll
        for (int kt = 0; kt < 2; ++kt) {
          bf16x8 bv = *reinterpret_cast<const bf16x8*>(w1 + (size_t)(nt * 16 + lr) * 64 + kt * 32 + lg * 8);
          c = __builtin_amdgcn_mfma_f32_16x16x32_bf16(a[mt][kt], bv, c, 0, 0, 0);
        }
        acc[mt][nt] = c;
      }
  }
  __syncthreads();
  #pragma unroll
  for (int nt = 0; nt < 8; ++nt) {
    float bb = b1[nt * 16 + lr];
    #pragma unroll
    for (int mt = 0; mt < 2; ++mt)
      #pragma unroll
      for (int r = 0; r < 4; ++r) {
        float v = acc[mt][nt][r] + bb;
        B[mt * 16 + lg * 4 + r][nt * 16 + lr] = f2b(v > 0.f ? v : 0.f);
      }
  }
  __syncthreads();

  // layer2: K=128 -> N=128 (u_embed)
  bf16x8 a2f[2][4];
  #pragma unroll
  for (int mt = 0; mt < 2; ++mt)
    #pragma unroll
    for (int kt = 0; kt < 4; ++kt)
      a2f[mt][kt] = *reinterpret_cast<const bf16x8*>(&B[mt * 16 + lr][kt * 32 + lg * 8]);
  #pragma unroll
  for (int nt = 0; nt < 8; ++nt)
    #pragma unroll
    for (int mt = 0; mt < 2; ++mt) {
      f32x4 c = {0.f, 0.f, 0.f, 0.f};
      #pragma unroll
      for (int kt = 0; kt < 4; ++kt) {
        bf16x8 bv = *reinterpret_cast<const bf16x8*>(w2 + (size_t)(nt * 16 + lr) * 128 + kt * 32 + lg * 8);
        c = __builtin_amdgcn_mfma_f32_16x16x32_bf16(a2f[mt][kt], bv, c, 0, 0, 0);
      }
      acc[mt][nt] = c;
    }
  __syncthreads();
  #pragma unroll
  for (int nt = 0; nt < 8; ++nt) {
    float bb = b2[nt * 16 + lr];
    #pragma unroll
    for (int mt = 0; mt < 2; ++mt)
      #pragma unroll
      for (int r = 0; r < 4; ++r) {
        float v = acc[mt][nt][r] + bb;
        B[mt * 16 + lg * 4 + r][nt * 16 + lr] = f2b(v > 0.f ? v : 0.f);
      }
  }
  __syncthreads();

  // gates: K=128 -> N=384, streamed per N-tile, written fp32 with bias
  bf16x8 ag[2][4];
  #pragma unroll
  for (int mt = 0; mt < 2; ++mt)
    #pragma unroll
    for (int kt = 0; kt < 4; ++kt)
      ag[mt][kt] = *reinterpret_cast<const bf16x8*>(&B[mt * 16 + lr][kt * 32 + lg * 8]);
  for (int nt = 0; nt < 24; ++nt) {
    float bb = bih[nt * 16 + lr];
    #pragma unroll
    for (int mt = 0; mt < 2; ++mt) {
      f32x4 c = {0.f, 0.f, 0.f, 0.f};
      #pragma unroll
      for (int kt = 0; kt < 4; ++kt) {
        bf16x8 bv = *reinterpret_cast<const bf16x8*>(wih + (size_t)(nt * 16 + lr) * 128 + kt * 32 + lg * 8);
        c = __builtin_amdgcn_mfma_f32_16x16x32_bf16(ag[mt][kt], bv, c, 0, 0, 0);
      }
      #pragma unroll
      for (int r = 0; r < 4; ++r)
        gates[(size_t)(m0 + mt * 16 + lg * 4 + r) * 384 + nt * 16 + lr] = c[r] + bb;
    }
  }
}

// ---------------------------------------------------------------------------
// K2: x-path: obs(128) -> relu fc(128) -> relu fc(128) = x_embed (output 4)
// ---------------------------------------------------------------------------
__global__ __launch_bounds__(256) void k_xpath(
    const float* __restrict__ obs, const short* __restrict__ w1, const float* __restrict__ b1,
    const short* __restrict__ w2, const float* __restrict__ b2,
    float* __restrict__ xe)
{
  __shared__ short buf[4][32][144];
  const int tid = threadIdx.x, w = tid >> 6, l = tid & 63;
  const int lr = l & 15, lg = l >> 4;
  const int m0 = blockIdx.x * 128 + w * 32;
  short (* __restrict__ B)[144] = buf[w];

  #pragma unroll
  for (int it = 0; it < 16; ++it) {
    int idx = (it * 64 + l) * 4;
    int row = idx >> 7, col = idx & 127;
    float4 v = *reinterpret_cast<const float4*>(obs + (size_t)(m0 + row) * 128 + col);
    bf16x4 p; p[0] = f2b(v.x); p[1] = f2b(v.y); p[2] = f2b(v.z); p[3] = f2b(v.w);
    *reinterpret_cast<bf16x4*>(&B[row][col]) = p;
  }
  __syncthreads();

  f32x4 acc[2][8];
  bf16x8 a1f[2][4];
  #pragma unroll
  for (int mt = 0; mt < 2; ++mt)
    #pragma unroll
    for (int kt = 0; kt < 4; ++kt)
      a1f[mt][kt] = *reinterpret_cast<const bf16x8*>(&B[mt * 16 + lr][kt * 32 + lg * 8]);
  #pragma unroll
  for (int nt = 0; nt < 8; ++nt)
    #pragma unroll
    for (int mt = 0; mt < 2; ++mt) {
      f32x4 c = {0.f, 0.f, 0.f, 0.f};
      #pragma unroll
      for (int kt = 0; kt < 4; ++kt) {
        bf16x8 bv = *reinterpret_cast<const bf16x8*>(w1 + (size_t)(nt * 16 + lr) * 128 + kt * 32 + lg * 8);
        c = __builtin_amdgcn_mfma_f32_16x16x32_bf16(a1f[mt][kt], bv, c, 0, 0, 0);
      }
      acc[mt][nt] = c;
    }
  __syncthreads();
  #pragma unroll
  for (int nt = 0; nt < 8; ++nt) {
    float bb = b1[nt * 16 + lr];
    #pragma unroll
    for (int mt = 0; mt < 2; ++mt)
      #pragma unroll
      for (int r = 0; r < 4; ++r) {
        float v = acc[mt][nt][r] + bb;
        B[mt * 16 + lg * 4 + r][nt * 16 + lr] = f2b(v > 0.f ? v : 0.f);
      }
  }
  __syncthreads();

  bf16x8 a2f[2][4];
  #pragma unroll
  for (int mt = 0; mt < 2; ++mt)
    #pragma unroll
    for (int kt = 0; kt < 4; ++kt)
      a2f[mt][kt] = *reinterpret_cast<const bf16x8*>(&B[mt * 16 + lr][kt * 32 + lg * 8]);
  #pragma unroll
  for (int nt = 0; nt < 8; ++nt) {
    float bb = b2[nt * 16 + lr];
    #pragma unroll
    for (int mt = 0; mt < 2; ++mt) {
      f32x4 c = {0.f, 0.f, 0.f, 0.f};
      #pragma unroll
      for (int kt = 0; kt < 4; ++kt) {
        bf16x8 bv = *reinterpret_cast<const bf16x8*>(w2 + (size_t)(nt * 16 + lr) * 128 + kt * 32 + lg * 8);
        c = __builtin_amdgcn_mfma_f32_16x16x32_bf16(a2f[mt][kt], bv, c, 0, 0, 0);
      }
      #pragma unroll
      for (int r = 0; r < 4; ++r) {
        float v = c[r] + bb;
        xe[(size_t)(m0 + mt * 16 + lg * 4 + r) * 128 + nt * 16 + lr] = (v > 0.f ? v : 0.f);
      }
    }
  }
}

// ---------------------------------------------------------------------------
// K3: GRU scan, v2. 32 blocks x 16 rows; wave w owns h-cols [32w,32w+32).
// Each wave computes its own r/z/n tiles (nt = g*8+2w+q) so the entire
// elementwise stage is in-register (r,z,n,h_old for the same (row,col) live
// in the same lane). h kept bf16 in double-buffered LDS (write D-layout,
// read A-layout); ONE barrier per step. Gates prefetched one step ahead
// into registers so L3 latency hides under the MFMA block.
// ---------------------------------------------------------------------------
__global__ __launch_bounds__(256) void k_gru(
    const float* __restrict__ gates, const short* __restrict__ whh,
    const float* __restrict__ bhh, float* __restrict__ hseq)
{
  __shared__ short hb[2][16][136];  // double-buffered h (bf16); stride 136 keeps
                                    // b128 reads 16B-aligned, bank-uniform
  const int tid = threadIdx.x, w = tid >> 6, l = tid & 63;
  const int lr = l & 15, lg = l >> 4;
  const int m0 = blockIdx.x * 16;

  // B-frags for this wave's 6 gate tiles: gate g in {r,z,n}, q in {0,1}
  // gate column = g*128 + (2w+q)*16 + lr
  bf16x8 bfr[3][2][4];
  float bb[3][2];
  #pragma unroll
  for (int g = 0; g < 3; ++g)
    #pragma unroll
    for (int q = 0; q < 2; ++q) {
      int col = g * 128 + (2 * w + q) * 16 + lr;
      bb[g][q] = bhh[col];
      #pragma unroll
      for (int kt = 0; kt < 4; ++kt)
        bfr[g][q][kt] = *reinterpret_cast<const bf16x8*>(whh + (size_t)col * 128 + kt * 32 + lg * 8);
    }

  // zero initial h buffer
  for (int i = tid; i < 16 * 136; i += 256) (&hb[0][0][0])[i] = 0;

  float hold[2][4];  // h_old[m = lg*4+r][c = (2w+q)*16+lr], carried in regs
  #pragma unroll
  for (int q = 0; q < 2; ++q)
    #pragma unroll
    for (int r = 0; r < 4; ++r) hold[q][r] = 0.f;

  // prefetch gates for t=0
  float gx[3][2][4];
  #pragma unroll
  for (int g = 0; g < 3; ++g)
    #pragma unroll
    for (int q = 0; q < 2; ++q)
      #pragma unroll
      for (int r = 0; r < 4; ++r)
        gx[g][q][r] = gates[((size_t)(m0 + lg * 4 + r)) * 384 + g * 128 + (2 * w + q) * 16 + lr];

  __syncthreads();

  #pragma unroll 2
  for (int t = 0; t < 256; ++t) {
    // issue next step's gate loads first (hide L3 latency under MFMAs)
    const int tn = (t + 1) & 255;
    float gn[3][2][4];
    #pragma unroll
    for (int g = 0; g < 3; ++g)
      #pragma unroll
      for (int q = 0; q < 2; ++q)
        #pragma unroll
        for (int r = 0; r < 4; ++r)
          gn[g][q][r] = gates[((size_t)tn * 512 + m0 + lg * 4 + r) * 384 + g * 128 + (2 * w + q) * 16 + lr];

    // A-frags of current h (bf16, direct)
    bf16x8 a[4];
    #pragma unroll
    for (int kt = 0; kt < 4; ++kt)
      a[kt] = *reinterpret_cast<const bf16x8*>(&hb[t & 1][lr][kt * 32 + lg * 8]);

    // hg = h @ whh^T for this wave's 6 tiles
    f32x4 acc[3][2];
    #pragma unroll
    for (int g = 0; g < 3; ++g)
      #pragma unroll
      for (int q = 0; q < 2; ++q) {
        f32x4 c = {0.f, 0.f, 0.f, 0.f};
        #pragma unroll
        for (int kt = 0; kt < 4; ++kt)
          c = __builtin_amdgcn_mfma_f32_16x16x32_bf16(a[kt], bfr[g][q][kt], c, 0, 0, 0);
        acc[g][q] = c;
      }

    // fully in-register elementwise + emit pre-update h + write h_new
    #pragma unroll
    for (int q = 0; q < 2; ++q) {
      const int c = (2 * w + q) * 16 + lr;
      #pragma unroll
      for (int r = 0; r < 4; ++r) {
        const int m = lg * 4 + r;
        float rr = sigm(gx[0][q][r] + acc[0][q][r] + bb[0][q]);
        float zz = sigm(gx[1][q][r] + acc[1][q][r] + bb[1][q]);
        float nn = tanh_fast(gx[2][q][r] + (acc[2][q][r] + bb[2][q]) * rr);
        float ho = hold[q][r];
        float hnew = (1.f - zz) * nn + zz * ho;
        hseq[((size_t)t * 512 + m0 + m) * 128 + c] = ho;  // pre-update h
        hold[q][r] = hnew;
        hb[(t + 1) & 1][m][c] = f2b(hnew);
      }
    }

    // rotate prefetched gates
    #pragma unroll
    for (int g = 0; g < 3; ++g)
      #pragma unroll
      for (int q = 0; q < 2; ++q)
        #pragma unroll
        for (int r = 0; r < 4; ++r)
          gx[g][q][r] = gn[g][q][r];

    __syncthreads();
  }
}

// ---------------------------------------------------------------------------
// K4: posterior DBlock + reparam sample. Block = 32 rows, 4 waves split N.
// ---------------------------------------------------------------------------
__global__ __launch_bounds__(256) void k_post(
    const float* __restrict__ xe, const float* __restrict__ hs, const float* __restrict__ eps,
    const short* __restrict__ pw1, const float* __restrict__ pb1,
    const short* __restrict__ pw2, const float* __restrict__ pb2,
    const short* __restrict__ pwmu, const float* __restrict__ pbmu,
    const short* __restrict__ pwls, const float* __restrict__ pbls,
    float* __restrict__ mu, float* __restrict__ ls, float* __restrict__ samp)
{
  __shared__ short bin[32][272];
  __shared__ short bt[32][272];
  const int tid = threadIdx.x, w = tid >> 6, l = tid & 63;
  const int lr = l & 15, lg = l >> 4;
  const int m0 = blockIdx.x * 32;

  #pragma unroll
  for (int it = 0; it < 8; ++it) {
    int idx = (it * 256 + tid) * 4;
    int row = idx >> 8, col = idx & 255;
    const float* src = (col < 128) ? (xe + (size_t)(m0 + row) * 128 + col)
                                   : (hs + (size_t)(m0 + row) * 128 + (col - 128));
    float4 v = *reinterpret_cast<const float4*>(src);
    bf16x4 p; p[0] = f2b(v.x); p[1] = f2b(v.y); p[2] = f2b(v.z); p[3] = f2b(v.w);
    *reinterpret_cast<bf16x4*>(&bin[row][col]) = p;
  }
  __syncthreads();

  f32x4 a1[2][4], a2[2][4];
  #pragma unroll
  for (int mt = 0; mt < 2; ++mt)
    #pragma unroll
    for (int j = 0; j < 4; ++j) { a1[mt][j] = (f32x4){0.f,0.f,0.f,0.f}; a2[mt][j] = (f32x4){0.f,0.f,0.f,0.f}; }
  #pragma unroll
  for (int kt = 0; kt < 8; ++kt) {
    bf16x8 a[2];
    #pragma unroll
    for (int mt = 0; mt < 2; ++mt)
      a[mt] = *reinterpret_cast<const bf16x8*>(&bin[mt * 16 + lr][kt * 32 + lg * 8]);
    #pragma unroll
    for (int j = 0; j < 4; ++j) {
      int n = (4 * w + j) * 16 + lr;
      bf16x8 b1v = *reinterpret_cast<const bf16x8*>(pw1 + (size_t)n * 256 + kt * 32 + lg * 8);
      bf16x8 b2v = *reinterpret_cast<const bf16x8*>(pw2 + (size_t)n * 256 + kt * 32 + lg * 8);
      #pragma unroll
      for (int mt = 0; mt < 2; ++mt) {
        a1[mt][j] = __builtin_amdgcn_mfma_f32_16x16x32_bf16(a[mt], b1v, a1[mt][j], 0, 0, 0);
        a2[mt][j] = __builtin_amdgcn_mfma_f32_16x16x32_bf16(a[mt], b2v, a2[mt][j], 0, 0, 0);
      }
    }
  }
  #pragma unroll
  for (int j = 0; j < 4; ++j) {
    int n = (4 * w + j) * 16 + lr;
    float bb1 = pb1[n], bb2 = pb2[n];
    #pragma unroll
    for (int mt = 0; mt < 2; ++mt)
      #pragma unroll
      for (int r = 0; r < 4; ++r) {
        float t1 = a1[mt][j][r] + bb1; t1 = t1 > 0.f ? t1 : 0.f;
        float t2 = sigm(a2[mt][j][r] + bb2);
        bt[mt * 16 + lg * 4 + r][n] = f2b(t1 * t2);
      }
  }
  __syncthreads();

  f32x4 am[2][2], al[2][2];
  #pragma unroll
  for (int mt = 0; mt < 2; ++mt)
    #pragma unroll
    for (int j = 0; j < 2; ++j) { am[mt][j] = (f32x4){0.f,0.f,0.f,0.f}; al[mt][j] = (f32x4){0.f,0.f,0.f,0.f}; }
  #pragma unroll
  for (int kt = 0; kt < 8; ++kt) {
    bf16x8 a[2];
    #pragma unroll
    for (int mt = 0; mt < 2; ++mt)
      a[mt] = *reinterpret_cast<const bf16x8*>(&bt[mt * 16 + lr][kt * 32 + lg * 8]);
    #pragma unroll
    for (int j = 0; j < 2; ++j) {
      int n = (2 * w + j) * 16 + lr;
      bf16x8 bm = *reinterpret_cast<const bf16x8*>(pwmu + (size_t)n * 256 + kt * 32 + lg * 8);
      bf16x8 bl = *reinterpret_cast<const bf16x8*>(pwls + (size_t)n * 256 + kt * 32 + lg * 8);
      #pragma unroll
      for (int mt = 0; mt < 2; ++mt) {
        am[mt][j] = __builtin_amdgcn_mfma_f32_16x16x32_bf16(a[mt], bm, am[mt][j], 0, 0, 0);
        al[mt][j] = __builtin_amdgcn_mfma_f32_16x16x32_bf16(a[mt], bl, al[mt][j], 0, 0, 0);
      }
    }
  }
  #pragma unroll
  for (int j = 0; j < 2; ++j) {
    int col = (2 * w + j) * 16 + lr;
    float bm = pbmu[col], bl = pbls[col];
    #pragma unroll
    for (int mt = 0; mt < 2; ++mt)
      #pragma unroll
      for (int r = 0; r < 4; ++r) {
        size_t off = (size_t)(m0 + mt * 16 + lg * 4 + r) * 128 + col;
        float m_ = am[mt][j][r] + bm;
        float l_ = al[mt][j][r] + bl;
        mu[off] = m_;
        ls[off] = l_;
        samp[off] = m_ + __expf(l_) * eps[off];
      }
  }
}

// ---------------------------------------------------------------------------
extern "C" void kernel_launch(void* const* d_in, const int* in_sizes, int n_in,
                              void* d_out, int out_size, void* d_ws, size_t ws_size,
                              hipStream_t stream) {
  const float* ext   = (const float*)d_in[0];
  const float* obs   = (const float*)d_in[1];
  const float* eps   = (const float*)d_in[2];
  const float* u_w1  = (const float*)d_in[3];
  const float* u_b1  = (const float*)d_in[4];
  const float* u_w2  = (const float*)d_in[5];
  const float* u_b2  = (const float*)d_in[6];
  const float* x_w1  = (const float*)d_in[7];
  const float* x_b1  = (const float*)d_in[8];
  const float* x_w2  = (const float*)d_in[9];
  const float* x_b2  = (const float*)d_in[10];
  const float* pw1   = (const float*)d_in[11];
  const float* pb1   = (const float*)d_in[12];
  const float* pw2   = (const float*)d_in[13];
  const float* pb2   = (const float*)d_in[14];
  const float* pwmu  = (const float*)d_in[15];
  const float* pbmu  = (const float*)d_in[16];
  const float* pwls  = (const float*)d_in[17];
  const float* pbls  = (const float*)d_in[18];
  const float* g_wih = (const float*)d_in[19];
  const float* g_whh = (const float*)d_in[20];
  const float* g_bih = (const float*)d_in[21];
  const float* g_bhh = (const float*)d_in[22];

  float* out = (float*)d_out;
  float* o_mu = out;
  float* o_ls = out + 16777216;
  float* o_sp = out + 33554432;
  float* o_hs = out + 50331648;
  float* o_xe = out + 67108864;
  // x_gates scratch exactly occupies outputs 0..2 (3*L*B*128 = L*B*384 floats);
  // fully consumed by k_gru before k_post overwrites the region.
  float* gates = out;

  short* wb = (short*)d_ws;
  short* c_uw1  = wb + 0;
  short* c_uw2  = wb + 8192;
  short* c_xw1  = wb + 24576;
  short* c_xw2  = wb + 40960;
  short* c_wih  = wb + 57344;
  short* c_whh  = wb + 106496;
  short* c_pw1  = wb + 155648;
  short* c_pw2  = wb + 221184;
  short* c_pwmu = wb + 286720;
  short* c_pwls = wb + 319488;

  k_cvt<<<1376, 256, 0, stream>>>(u_w1, u_w2, x_w1, x_w2, g_wih, g_whh,
                                  pw1, pw2, pwmu, pwls, wb);
  k_upath<<<1024, 256, 0, stream>>>(ext, c_uw1, u_b1, c_uw2, u_b2, c_wih, g_bih, gates);
  k_xpath<<<1024, 256, 0, stream>>>(obs, c_xw1, x_b1, c_xw2, x_b2, o_xe);
  k_gru<<<32, 256, 0, stream>>>(gates, c_whh, g_bhh, o_hs);
  k_post<<<4096, 256, 0, stream>>>(o_xe, o_hs, eps, c_pw1, pb1, c_pw2, pb2,
                                   c_pwmu, pbmu, c_pwls, pbls, o_mu, o_ls, o_sp);
}

// Round 3
// 712.109 us; speedup vs baseline: 1.5203x; 1.1626x over previous
//
#include <hip/hip_runtime.h>

// ---------------------------------------------------------------------------
// VAERNN forward posterior, MI355X bf16-MFMA implementation.
// L=256 B=512 K=128 IN=64 STATE=128 OBS=128, LB = L*B = 131072 rows.
// ---------------------------------------------------------------------------

typedef __attribute__((ext_vector_type(8))) short bf16x8;
typedef __attribute__((ext_vector_type(4))) short bf16x4;
typedef __attribute__((ext_vector_type(4))) float f32x4;

#define LB 131072

__device__ __forceinline__ short f2b(float f) {
  union { float f; unsigned u; } v; v.f = f;
  unsigned r = (v.u + 0x7FFFu + ((v.u >> 16) & 1u)) >> 16;  // RNE
  return (short)r;
}
__device__ __forceinline__ float u2f(unsigned u) {
  union { unsigned u; float f; } v; v.u = u << 16; return v.f;
}
__device__ __forceinline__ float sigm(float x) { return 1.f / (1.f + __expf(-x)); }
__device__ __forceinline__ float tanh_fast(float x) { return 1.f - 2.f / (1.f + __expf(2.f * x)); }

// ---------------------------------------------------------------------------
// K0: convert all weight matrices fp32 -> bf16 into workspace (contiguous).
// ---------------------------------------------------------------------------
__global__ __launch_bounds__(256) void k_cvt(
    const float* __restrict__ s0, const float* __restrict__ s1,
    const float* __restrict__ s2, const float* __restrict__ s3,
    const float* __restrict__ s4, const float* __restrict__ s5,
    const float* __restrict__ s6, const float* __restrict__ s7,
    const float* __restrict__ s8, const float* __restrict__ s9,
    short* __restrict__ dst)
{
  int i = blockIdx.x * 256 + threadIdx.x;
  if (i >= 352256) return;
  const float* src; int off;
  if      (i <   8192) { src = s0; off = i; }
  else if (i <  24576) { src = s1; off = i - 8192; }
  else if (i <  40960) { src = s2; off = i - 24576; }
  else if (i <  57344) { src = s3; off = i - 40960; }
  else if (i < 106496) { src = s4; off = i - 57344; }
  else if (i < 155648) { src = s5; off = i - 106496; }
  else if (i < 221184) { src = s6; off = i - 155648; }
  else if (i < 286720) { src = s7; off = i - 221184; }
  else if (i < 319488) { src = s8; off = i - 286720; }
  else                 { src = s9; off = i - 319488; }
  dst[i] = f2b(src[off]);
}

// ---------------------------------------------------------------------------
// K1: u-path: x(64) -> relu fc(128) -> relu fc(128) -> gates GEMM (384), all
// fused. Writes x_gates as BF16 (with bih added) to scratch.
// ---------------------------------------------------------------------------
__global__ __launch_bounds__(256) void k_upath(
    const float* __restrict__ x, const short* __restrict__ w1, const float* __restrict__ b1,
    const short* __restrict__ w2, const float* __restrict__ b2,
    const short* __restrict__ wih, const float* __restrict__ bih,
    short* __restrict__ gates)
{
  __shared__ short buf[4][32][144];
  const int tid = threadIdx.x, w = tid >> 6, l = tid & 63;
  const int lr = l & 15, lg = l >> 4;
  const int m0 = blockIdx.x * 128 + w * 32;
  short (* __restrict__ B)[144] = buf[w];

  #pragma unroll
  for (int it = 0; it < 8; ++it) {
    int idx = (it * 64 + l) * 4;
    int row = idx >> 6, col = idx & 63;
    float4 v = *reinterpret_cast<const float4*>(x + (size_t)(m0 + row) * 64 + col);
    bf16x4 p; p[0] = f2b(v.x); p[1] = f2b(v.y); p[2] = f2b(v.z); p[3] = f2b(v.w);
    *reinterpret_cast<bf16x4*>(&B[row][col]) = p;
  }
  __syncthreads();

  f32x4 acc[2][8];

  // layer1: K=64 -> N=128
  {
    bf16x8 a[2][2];
    #pragma unroll
    for (int mt = 0; mt < 2; ++mt)
      #pragma unroll
      for (int kt = 0; kt < 2; ++kt)
        a[mt][kt] = *reinterpret_cast<const bf16x8*>(&B[mt * 16 + lr][kt * 32 + lg * 8]);
    #pragma unroll
    for (int nt = 0; nt < 8; ++nt)
      #pragma unroll
      for (int mt = 0; mt < 2; ++mt) {
        f32x4 c = {0.f, 0.f, 0.f, 0.f};
        #pragma unroll
        for (int kt = 0; kt < 2; ++kt) {
          bf16x8 bv = *reinterpret_cast<const bf16x8*>(w1 + (size_t)(nt * 16 + lr) * 64 + kt * 32 + lg * 8);
          c = __builtin_amdgcn_mfma_f32_16x16x32_bf16(a[mt][kt], bv, c, 0, 0, 0);
        }
        acc[mt][nt] = c;
      }
  }
  __syncthreads();
  #pragma unroll
  for (int nt = 0; nt < 8; ++nt) {
    float bb = b1[nt * 16 + lr];
    #pragma unroll
    for (int mt = 0; mt < 2; ++mt)
      #pragma unroll
      for (int r = 0; r < 4; ++r) {
        float v = acc[mt][nt][r] + bb;
        B[mt * 16 + lg * 4 + r][nt * 16 + lr] = f2b(v > 0.f ? v : 0.f);
      }
  }
  __syncthreads();

  // layer2: K=128 -> N=128 (u_embed)
  bf16x8 a2f[2][4];
  #pragma unroll
  for (int mt = 0; mt < 2; ++mt)
    #pragma unroll
    for (int kt = 0; kt < 4; ++kt)
      a2f[mt][kt] = *reinterpret_cast<const bf16x8*>(&B[mt * 16 + lr][kt * 32 + lg * 8]);
  #pragma unroll
  for (int nt = 0; nt < 8; ++nt)
    #pragma unroll
    for (int mt = 0; mt < 2; ++mt) {
      f32x4 c = {0.f, 0.f, 0.f, 0.f};
      #pragma unroll
      for (int kt = 0; kt < 4; ++kt) {
        bf16x8 bv = *reinterpret_cast<const bf16x8*>(w2 + (size_t)(nt * 16 + lr) * 128 + kt * 32 + lg * 8);
        c = __builtin_amdgcn_mfma_f32_16x16x32_bf16(a2f[mt][kt], bv, c, 0, 0, 0);
      }
      acc[mt][nt] = c;
    }
  __syncthreads();
  #pragma unroll
  for (int nt = 0; nt < 8; ++nt) {
    float bb = b2[nt * 16 + lr];
    #pragma unroll
    for (int mt = 0; mt < 2; ++mt)
      #pragma unroll
      for (int r = 0; r < 4; ++r) {
        float v = acc[mt][nt][r] + bb;
        B[mt * 16 + lg * 4 + r][nt * 16 + lr] = f2b(v > 0.f ? v : 0.f);
      }
  }
  __syncthreads();

  // gates: K=128 -> N=384, streamed per N-tile, written bf16 with bias
  bf16x8 ag[2][4];
  #pragma unroll
  for (int mt = 0; mt < 2; ++mt)
    #pragma unroll
    for (int kt = 0; kt < 4; ++kt)
      ag[mt][kt] = *reinterpret_cast<const bf16x8*>(&B[mt * 16 + lr][kt * 32 + lg * 8]);
  for (int nt = 0; nt < 24; ++nt) {
    float bb = bih[nt * 16 + lr];
    #pragma unroll
    for (int mt = 0; mt < 2; ++mt) {
      f32x4 c = {0.f, 0.f, 0.f, 0.f};
      #pragma unroll
      for (int kt = 0; kt < 4; ++kt) {
        bf16x8 bv = *reinterpret_cast<const bf16x8*>(wih + (size_t)(nt * 16 + lr) * 128 + kt * 32 + lg * 8);
        c = __builtin_amdgcn_mfma_f32_16x16x32_bf16(ag[mt][kt], bv, c, 0, 0, 0);
      }
      #pragma unroll
      for (int r = 0; r < 4; ++r)
        gates[(size_t)(m0 + mt * 16 + lg * 4 + r) * 384 + nt * 16 + lr] = f2b(c[r] + bb);
    }
  }
}

// ---------------------------------------------------------------------------
// K2: x-path: obs(128) -> relu fc(128) -> relu fc(128) = x_embed (output 4)
// ---------------------------------------------------------------------------
__global__ __launch_bounds__(256) void k_xpath(
    const float* __restrict__ obs, const short* __restrict__ w1, const float* __restrict__ b1,
    const short* __restrict__ w2, const float* __restrict__ b2,
    float* __restrict__ xe)
{
  __shared__ short buf[4][32][144];
  const int tid = threadIdx.x, w = tid >> 6, l = tid & 63;
  const int lr = l & 15, lg = l >> 4;
  const int m0 = blockIdx.x * 128 + w * 32;
  short (* __restrict__ B)[144] = buf[w];

  #pragma unroll
  for (int it = 0; it < 16; ++it) {
    int idx = (it * 64 + l) * 4;
    int row = idx >> 7, col = idx & 127;
    float4 v = *reinterpret_cast<const float4*>(obs + (size_t)(m0 + row) * 128 + col);
    bf16x4 p; p[0] = f2b(v.x); p[1] = f2b(v.y); p[2] = f2b(v.z); p[3] = f2b(v.w);
    *reinterpret_cast<bf16x4*>(&B[row][col]) = p;
  }
  __syncthreads();

  f32x4 acc[2][8];
  bf16x8 a1f[2][4];
  #pragma unroll
  for (int mt = 0; mt < 2; ++mt)
    #pragma unroll
    for (int kt = 0; kt < 4; ++kt)
      a1f[mt][kt] = *reinterpret_cast<const bf16x8*>(&B[mt * 16 + lr][kt * 32 + lg * 8]);
  #pragma unroll
  for (int nt = 0; nt < 8; ++nt)
    #pragma unroll
    for (int mt = 0; mt < 2; ++mt) {
      f32x4 c = {0.f, 0.f, 0.f, 0.f};
      #pragma unroll
      for (int kt = 0; kt < 4; ++kt) {
        bf16x8 bv = *reinterpret_cast<const bf16x8*>(w1 + (size_t)(nt * 16 + lr) * 128 + kt * 32 + lg * 8);
        c = __builtin_amdgcn_mfma_f32_16x16x32_bf16(a1f[mt][kt], bv, c, 0, 0, 0);
      }
      acc[mt][nt] = c;
    }
  __syncthreads();
  #pragma unroll
  for (int nt = 0; nt < 8; ++nt) {
    float bb = b1[nt * 16 + lr];
    #pragma unroll
    for (int mt = 0; mt < 2; ++mt)
      #pragma unroll
      for (int r = 0; r < 4; ++r) {
        float v = acc[mt][nt][r] + bb;
        B[mt * 16 + lg * 4 + r][nt * 16 + lr] = f2b(v > 0.f ? v : 0.f);
      }
  }
  __syncthreads();

  bf16x8 a2f[2][4];
  #pragma unroll
  for (int mt = 0; mt < 2; ++mt)
    #pragma unroll
    for (int kt = 0; kt < 4; ++kt)
      a2f[mt][kt] = *reinterpret_cast<const bf16x8*>(&B[mt * 16 + lr][kt * 32 + lg * 8]);
  #pragma unroll
  for (int nt = 0; nt < 8; ++nt) {
    float bb = b2[nt * 16 + lr];
    #pragma unroll
    for (int mt = 0; mt < 2; ++mt) {
      f32x4 c = {0.f, 0.f, 0.f, 0.f};
      #pragma unroll
      for (int kt = 0; kt < 4; ++kt) {
        bf16x8 bv = *reinterpret_cast<const bf16x8*>(w2 + (size_t)(nt * 16 + lr) * 128 + kt * 32 + lg * 8);
        c = __builtin_amdgcn_mfma_f32_16x16x32_bf16(a2f[mt][kt], bv, c, 0, 0, 0);
      }
      #pragma unroll
      for (int r = 0; r < 4; ++r) {
        float v = c[r] + bb;
        xe[(size_t)(m0 + mt * 16 + lg * 4 + r) * 128 + nt * 16 + lr] = (v > 0.f ? v : 0.f);
      }
    }
  }
}

// ---------------------------------------------------------------------------
// K3: GRU scan, v3. 32 blocks x 512 threads (8 waves); block owns 16 batch
// rows; wave w owns h-cols [16w,16w+16) for ALL three gates -> elementwise
// fully in-register, h_old carried in regs. h bf16 in double-buffered LDS.
// Raw s_barrier + lgkmcnt(0)-only wait: global loads/stores stay in flight
// across barriers (no vmcnt(0) drain). Gates prefetched 1 step ahead into
// explicitly double-buffered named register sets (no rotate copy).
// ---------------------------------------------------------------------------
__global__ __launch_bounds__(512) void k_gru(
    const short* __restrict__ gates, const short* __restrict__ whh,
    const float* __restrict__ bhh, float* __restrict__ hseq)
{
  __shared__ short hb[2][16][136];
  const int tid = threadIdx.x, w = tid >> 6, l = tid & 63;
  const int lr = l & 15, lg = l >> 4;
  const int m0 = blockIdx.x * 16;
  const int c = w * 16 + lr;  // this lane's h/gate column (0..127)

  // B-frags: gate g at col g*128 + c
  bf16x8 bfr[3][4];
  float bb[3];
  #pragma unroll
  for (int g = 0; g < 3; ++g) {
    bb[g] = bhh[g * 128 + c];
    #pragma unroll
    for (int kt = 0; kt < 4; ++kt)
      bfr[g][kt] = *reinterpret_cast<const bf16x8*>(whh + (size_t)(g * 128 + c) * 128 + kt * 32 + lg * 8);
  }

  for (int i = tid; i < 16 * 136; i += 512) (&hb[0][0][0])[i] = 0;

  float hold[4] = {0.f, 0.f, 0.f, 0.f};

  unsigned gA[3][4], gB[3][4];
  #pragma unroll
  for (int g = 0; g < 3; ++g)
    #pragma unroll
    for (int r = 0; r < 4; ++r)
      gA[g][r] = (unsigned short)gates[((size_t)(m0 + lg * 4 + r)) * 384 + g * 128 + c];

  __syncthreads();

#define GRU_STEP(T, GC, GN, BR, BW)                                            \
  {                                                                            \
    const int t_ = (T);                                                        \
    const int tn_ = (t_ + 1) & 255;                                            \
    _Pragma("unroll")                                                          \
    for (int g = 0; g < 3; ++g)                                                \
      _Pragma("unroll")                                                        \
      for (int r = 0; r < 4; ++r)                                              \
        GN[g][r] = (unsigned short)gates[((size_t)tn_ * 512 + m0 + lg * 4 + r) * 384 + g * 128 + c]; \
    bf16x8 a_[4];                                                              \
    _Pragma("unroll")                                                          \
    for (int kt = 0; kt < 4; ++kt)                                             \
      a_[kt] = *reinterpret_cast<const bf16x8*>(&hb[BR][lr][kt * 32 + lg * 8]);\
    f32x4 acc_[3];                                                             \
    _Pragma("unroll")                                                          \
    for (int g = 0; g < 3; ++g) {                                              \
      f32x4 cc = {0.f, 0.f, 0.f, 0.f};                                         \
      _Pragma("unroll")                                                        \
      for (int kt = 0; kt < 4; ++kt)                                           \
        cc = __builtin_amdgcn_mfma_f32_16x16x32_bf16(a_[kt], bfr[g][kt], cc, 0, 0, 0); \
      acc_[g] = cc;                                                            \
    }                                                                          \
    _Pragma("unroll")                                                          \
    for (int r = 0; r < 4; ++r) {                                              \
      const int m = lg * 4 + r;                                                \
      float rr = sigm(u2f(GC[0][r]) + acc_[0][r] + bb[0]);                     \
      float zz = sigm(u2f(GC[1][r]) + acc_[1][r] + bb[1]);                     \
      float nn = tanh_fast(u2f(GC[2][r]) + (acc_[2][r] + bb[2]) * rr);         \
      float ho = hold[r];                                                      \
      float hnew = (1.f - zz) * nn + zz * ho;                                  \
      hseq[((size_t)t_ * 512 + m0 + m) * 128 + c] = ho;                        \
      hold[r] = hnew;                                                          \
      hb[BW][m][c] = f2b(hnew);                                                \
    }                                                                          \
    asm volatile("s_waitcnt lgkmcnt(0)" ::: "memory");                         \
    __builtin_amdgcn_s_barrier();                                              \
    __builtin_amdgcn_sched_barrier(0);                                         \
  }

  for (int tt = 0; tt < 128; ++tt) {
    GRU_STEP(2 * tt,     gA, gB, 0, 1)
    GRU_STEP(2 * tt + 1, gB, gA, 1, 0)
  }
#undef GRU_STEP
}

// ---------------------------------------------------------------------------
// K4: posterior DBlock + reparam sample. Block = 64 rows (halves weight
// re-streaming from L2 vs 32), 4 waves split N.
// ---------------------------------------------------------------------------
__global__ __launch_bounds__(256) void k_post(
    const float* __restrict__ xe, const float* __restrict__ hs, const float* __restrict__ eps,
    const short* __restrict__ pw1, const float* __restrict__ pb1,
    const short* __restrict__ pw2, const float* __restrict__ pb2,
    const short* __restrict__ pwmu, const float* __restrict__ pbmu,
    const short* __restrict__ pwls, const float* __restrict__ pbls,
    float* __restrict__ mu, float* __restrict__ ls, float* __restrict__ samp)
{
  __shared__ short bin[64][272];
  __shared__ short bt[64][272];
  const int tid = threadIdx.x, w = tid >> 6, l = tid & 63;
  const int lr = l & 15, lg = l >> 4;
  const int m0 = blockIdx.x * 64;

  // stage post_in = [x_embed | h_seq] 64 rows x 256 cols as bf16
  #pragma unroll
  for (int it = 0; it < 16; ++it) {
    int idx = (it * 256 + tid) * 4;
    int row = idx >> 8, col = idx & 255;
    const float* src = (col < 128) ? (xe + (size_t)(m0 + row) * 128 + col)
                                   : (hs + (size_t)(m0 + row) * 128 + (col - 128));
    float4 v = *reinterpret_cast<const float4*>(src);
    bf16x4 p; p[0] = f2b(v.x); p[1] = f2b(v.y); p[2] = f2b(v.z); p[3] = f2b(v.w);
    *reinterpret_cast<bf16x4*>(&bin[row][col]) = p;
  }
  __syncthreads();

  // fc1 (relu) * sigmoid(fc2): wave w owns cols [64w, 64w+64)
  f32x4 a1[4][4], a2[4][4];
  #pragma unroll
  for (int mt = 0; mt < 4; ++mt)
    #pragma unroll
    for (int j = 0; j < 4; ++j) { a1[mt][j] = (f32x4){0.f,0.f,0.f,0.f}; a2[mt][j] = (f32x4){0.f,0.f,0.f,0.f}; }
  #pragma unroll
  for (int kt = 0; kt < 8; ++kt) {
    bf16x8 a[4];
    #pragma unroll
    for (int mt = 0; mt < 4; ++mt)
      a[mt] = *reinterpret_cast<const bf16x8*>(&bin[mt * 16 + lr][kt * 32 + lg * 8]);
    #pragma unroll
    for (int j = 0; j < 4; ++j) {
      int n = (4 * w + j) * 16 + lr;
      bf16x8 b1v = *reinterpret_cast<const bf16x8*>(pw1 + (size_t)n * 256 + kt * 32 + lg * 8);
      bf16x8 b2v = *reinterpret_cast<const bf16x8*>(pw2 + (size_t)n * 256 + kt * 32 + lg * 8);
      #pragma unroll
      for (int mt = 0; mt < 4; ++mt) {
        a1[mt][j] = __builtin_amdgcn_mfma_f32_16x16x32_bf16(a[mt], b1v, a1[mt][j], 0, 0, 0);
        a2[mt][j] = __builtin_amdgcn_mfma_f32_16x16x32_bf16(a[mt], b2v, a2[mt][j], 0, 0, 0);
      }
    }
  }
  #pragma unroll
  for (int j = 0; j < 4; ++j) {
    int n = (4 * w + j) * 16 + lr;
    float bb1 = pb1[n], bb2 = pb2[n];
    #pragma unroll
    for (int mt = 0; mt < 4; ++mt)
      #pragma unroll
      for (int r = 0; r < 4; ++r) {
        float t1 = a1[mt][j][r] + bb1; t1 = t1 > 0.f ? t1 : 0.f;
        float t2 = sigm(a2[mt][j][r] + bb2);
        bt[mt * 16 + lg * 4 + r][n] = f2b(t1 * t2);
      }
  }
  __syncthreads();

  // mu/ls: wave w owns cols [32w, 32w+32) of each
  f32x4 am[4][2], al[4][2];
  #pragma unroll
  for (int mt = 0; mt < 4; ++mt)
    #pragma unroll
    for (int j = 0; j < 2; ++j) { am[mt][j] = (f32x4){0.f,0.f,0.f,0.f}; al[mt][j] = (f32x4){0.f,0.f,0.f,0.f}; }
  #pragma unroll
  for (int kt = 0; kt < 8; ++kt) {
    bf16x8 a[4];
    #pragma unroll
    for (int mt = 0; mt < 4; ++mt)
      a[mt] = *reinterpret_cast<const bf16x8*>(&bt[mt * 16 + lr][kt * 32 + lg * 8]);
    #pragma unroll
    for (int j = 0; j < 2; ++j) {
      int n = (2 * w + j) * 16 + lr;
      bf16x8 bm = *reinterpret_cast<const bf16x8*>(pwmu + (size_t)n * 256 + kt * 32 + lg * 8);
      bf16x8 bl = *reinterpret_cast<const bf16x8*>(pwls + (size_t)n * 256 + kt * 32 + lg * 8);
      #pragma unroll
      for (int mt = 0; mt < 4; ++mt) {
        am[mt][j] = __builtin_amdgcn_mfma_f32_16x16x32_bf16(a[mt], bm, am[mt][j], 0, 0, 0);
        al[mt][j] = __builtin_amdgcn_mfma_f32_16x16x32_bf16(a[mt], bl, al[mt][j], 0, 0, 0);
      }
    }
  }
  #pragma unroll
  for (int j = 0; j < 2; ++j) {
    int col = (2 * w + j) * 16 + lr;
    float bm = pbmu[col], bl = pbls[col];
    #pragma unroll
    for (int mt = 0; mt < 4; ++mt)
      #pragma unroll
      for (int r = 0; r < 4; ++r) {
        size_t off = (size_t)(m0 + mt * 16 + lg * 4 + r) * 128 + col;
        float m_ = am[mt][j][r] + bm;
        float l_ = al[mt][j][r] + bl;
        mu[off] = m_;
        ls[off] = l_;
        samp[off] = m_ + __expf(l_) * eps[off];
      }
  }
}

// ---------------------------------------------------------------------------
extern "C" void kernel_launch(void* const* d_in, const int* in_sizes, int n_in,
                              void* d_out, int out_size, void* d_ws, size_t ws_size,
                              hipStream_t stream) {
  const float* ext   = (const float*)d_in[0];
  const float* obs   = (const float*)d_in[1];
  const float* eps   = (const float*)d_in[2];
  const float* u_w1  = (const float*)d_in[3];
  const float* u_b1  = (const float*)d_in[4];
  const float* u_w2  = (const float*)d_in[5];
  const float* u_b2  = (const float*)d_in[6];
  const float* x_w1  = (const float*)d_in[7];
  const float* x_b1  = (const float*)d_in[8];
  const float* x_w2  = (const float*)d_in[9];
  const float* x_b2  = (const float*)d_in[10];
  const float* pw1   = (const float*)d_in[11];
  const float* pb1   = (const float*)d_in[12];
  const float* pw2   = (const float*)d_in[13];
  const float* pb2   = (const float*)d_in[14];
  const float* pwmu  = (const float*)d_in[15];
  const float* pbmu  = (const float*)d_in[16];
  const float* pwls  = (const float*)d_in[17];
  const float* pbls  = (const float*)d_in[18];
  const float* g_wih = (const float*)d_in[19];
  const float* g_whh = (const float*)d_in[20];
  const float* g_bih = (const float*)d_in[21];
  const float* g_bhh = (const float*)d_in[22];

  float* out = (float*)d_out;
  float* o_mu = out;
  float* o_ls = out + 16777216;
  float* o_sp = out + 33554432;
  float* o_hs = out + 50331648;
  float* o_xe = out + 67108864;
  // bf16 x_gates scratch (L*B*384 shorts = 100 MB) lives at the start of the
  // output region (mu + part of ls); fully consumed by k_gru before k_post
  // overwrites the region.
  short* gates = (short*)out;

  short* wb = (short*)d_ws;
  short* c_uw1  = wb + 0;
  short* c_uw2  = wb + 8192;
  short* c_xw1  = wb + 24576;
  short* c_xw2  = wb + 40960;
  short* c_wih  = wb + 57344;
  short* c_whh  = wb + 106496;
  short* c_pw1  = wb + 155648;
  short* c_pw2  = wb + 221184;
  short* c_pwmu = wb + 286720;
  short* c_pwls = wb + 319488;

  k_cvt<<<1376, 256, 0, stream>>>(u_w1, u_w2, x_w1, x_w2, g_wih, g_whh,
                                  pw1, pw2, pwmu, pwls, wb);
  k_upath<<<1024, 256, 0, stream>>>(ext, c_uw1, u_b1, c_uw2, u_b2, c_wih, g_bih, gates);
  k_xpath<<<1024, 256, 0, stream>>>(obs, c_xw1, x_b1, c_xw2, x_b2, o_xe);
  k_gru<<<32, 512, 0, stream>>>(gates, c_whh, g_bhh, o_hs);
  k_post<<<2048, 256, 0, stream>>>(o_xe, o_hs, eps, c_pw1, pb1, c_pw2, pb2,
                                   c_pwmu, pbmu, c_pwls, pbls, o_mu, o_ls, o_sp);
}

// Round 4
// 626.845 us; speedup vs baseline: 1.7270x; 1.1360x over previous
//
#include <hip/hip_runtime.h>

// ---------------------------------------------------------------------------
// VAERNN forward posterior, MI355X bf16-MFMA implementation.
// L=256 B=512 K=128 IN=64 STATE=128 OBS=128, LB = L*B = 131072 rows.
// ---------------------------------------------------------------------------

typedef __attribute__((ext_vector_type(8))) short bf16x8;
typedef __attribute__((ext_vector_type(4))) short bf16x4;
typedef __attribute__((ext_vector_type(4))) float f32x4;

#define LB 131072

__device__ __forceinline__ short f2b(float f) {
  union { float f; unsigned u; } v; v.f = f;
  unsigned r = (v.u + 0x7FFFu + ((v.u >> 16) & 1u)) >> 16;  // RNE
  return (short)r;
}
__device__ __forceinline__ float u2f(unsigned u) {
  union { unsigned u; float f; } v; v.u = u << 16; return v.f;
}
__device__ __forceinline__ float rcpf(float x) { return __builtin_amdgcn_rcpf(x); }
__device__ __forceinline__ float exp2f_(float x) { return __builtin_amdgcn_exp2f(x); }
__device__ __forceinline__ float sigm(float x) { return rcpf(1.f + exp2f_(-1.44269504f * x)); }

// ---------------------------------------------------------------------------
// K0: convert all weight matrices fp32 -> bf16 into workspace (contiguous).
// ---------------------------------------------------------------------------
__global__ __launch_bounds__(256) void k_cvt(
    const float* __restrict__ s0, const float* __restrict__ s1,
    const float* __restrict__ s2, const float* __restrict__ s3,
    const float* __restrict__ s4, const float* __restrict__ s5,
    const float* __restrict__ s6, const float* __restrict__ s7,
    const float* __restrict__ s8, const float* __restrict__ s9,
    short* __restrict__ dst)
{
  int i = blockIdx.x * 256 + threadIdx.x;
  if (i >= 352256) return;
  const float* src; int off;
  if      (i <   8192) { src = s0; off = i; }
  else if (i <  24576) { src = s1; off = i - 8192; }
  else if (i <  40960) { src = s2; off = i - 24576; }
  else if (i <  57344) { src = s3; off = i - 40960; }
  else if (i < 106496) { src = s4; off = i - 57344; }
  else if (i < 155648) { src = s5; off = i - 106496; }
  else if (i < 221184) { src = s6; off = i - 155648; }
  else if (i < 286720) { src = s7; off = i - 221184; }
  else if (i < 319488) { src = s8; off = i - 286720; }
  else                 { src = s9; off = i - 319488; }
  dst[i] = f2b(src[off]);
}

// ---------------------------------------------------------------------------
// K1: u-path: x(64) -> relu fc(128) -> relu fc(128) -> gates GEMM (384), all
// fused. Writes x_gates as BF16 to scratch. Bias: bih + (bhh for r/z gates
// only — bhh_n must stay separate since it multiplies with r in the GRU).
// ---------------------------------------------------------------------------
__global__ __launch_bounds__(256) void k_upath(
    const float* __restrict__ x, const short* __restrict__ w1, const float* __restrict__ b1,
    const short* __restrict__ w2, const float* __restrict__ b2,
    const short* __restrict__ wih, const float* __restrict__ bih,
    const float* __restrict__ bhh,
    short* __restrict__ gates)
{
  __shared__ short buf[4][32][144];
  const int tid = threadIdx.x, w = tid >> 6, l = tid & 63;
  const int lr = l & 15, lg = l >> 4;
  const int m0 = blockIdx.x * 128 + w * 32;
  short (* __restrict__ B)[144] = buf[w];

  #pragma unroll
  for (int it = 0; it < 8; ++it) {
    int idx = (it * 64 + l) * 4;
    int row = idx >> 6, col = idx & 63;
    float4 v = *reinterpret_cast<const float4*>(x + (size_t)(m0 + row) * 64 + col);
    bf16x4 p; p[0] = f2b(v.x); p[1] = f2b(v.y); p[2] = f2b(v.z); p[3] = f2b(v.w);
    *reinterpret_cast<bf16x4*>(&B[row][col]) = p;
  }
  __syncthreads();

  f32x4 acc[2][8];

  // layer1: K=64 -> N=128
  {
    bf16x8 a[2][2];
    #pragma unroll
    for (int mt = 0; mt < 2; ++mt)
      #pragma unroll
      for (int kt = 0; kt < 2; ++kt)
        a[mt][kt] = *reinterpret_cast<const bf16x8*>(&B[mt * 16 + lr][kt * 32 + lg * 8]);
    #pragma unroll
    for (int nt = 0; nt < 8; ++nt)
      #pragma unroll
      for (int mt = 0; mt < 2; ++mt) {
        f32x4 c = {0.f, 0.f, 0.f, 0.f};
        #pragma unroll
        for (int kt = 0; kt < 2; ++kt) {
          bf16x8 bv = *reinterpret_cast<const bf16x8*>(w1 + (size_t)(nt * 16 + lr) * 64 + kt * 32 + lg * 8);
          c = __builtin_amdgcn_mfma_f32_16x16x32_bf16(a[mt][kt], bv, c, 0, 0, 0);
        }
        acc[mt][nt] = c;
      }
  }
  __syncthreads();
  #pragma unroll
  for (int nt = 0; nt < 8; ++nt) {
    float bb = b1[nt * 16 + lr];
    #pragma unroll
    for (int mt = 0; mt < 2; ++mt)
      #pragma unroll
      for (int r = 0; r < 4; ++r) {
        float v = acc[mt][nt][r] + bb;
        B[mt * 16 + lg * 4 + r][nt * 16 + lr] = f2b(v > 0.f ? v : 0.f);
      }
  }
  __syncthreads();

  // layer2: K=128 -> N=128 (u_embed)
  bf16x8 a2f[2][4];
  #pragma unroll
  for (int mt = 0; mt < 2; ++mt)
    #pragma unroll
    for (int kt = 0; kt < 4; ++kt)
      a2f[mt][kt] = *reinterpret_cast<const bf16x8*>(&B[mt * 16 + lr][kt * 32 + lg * 8]);
  #pragma unroll
  for (int nt = 0; nt < 8; ++nt)
    #pragma unroll
    for (int mt = 0; mt < 2; ++mt) {
      f32x4 c = {0.f, 0.f, 0.f, 0.f};
      #pragma unroll
      for (int kt = 0; kt < 4; ++kt) {
        bf16x8 bv = *reinterpret_cast<const bf16x8*>(w2 + (size_t)(nt * 16 + lr) * 128 + kt * 32 + lg * 8);
        c = __builtin_amdgcn_mfma_f32_16x16x32_bf16(a2f[mt][kt], bv, c, 0, 0, 0);
      }
      acc[mt][nt] = c;
    }
  __syncthreads();
  #pragma unroll
  for (int nt = 0; nt < 8; ++nt) {
    float bb = b2[nt * 16 + lr];
    #pragma unroll
    for (int mt = 0; mt < 2; ++mt)
      #pragma unroll
      for (int r = 0; r < 4; ++r) {
        float v = acc[mt][nt][r] + bb;
        B[mt * 16 + lg * 4 + r][nt * 16 + lr] = f2b(v > 0.f ? v : 0.f);
      }
  }
  __syncthreads();

  // gates: K=128 -> N=384, streamed per N-tile, written bf16 with fused bias
  bf16x8 ag[2][4];
  #pragma unroll
  for (int mt = 0; mt < 2; ++mt)
    #pragma unroll
    for (int kt = 0; kt < 4; ++kt)
      ag[mt][kt] = *reinterpret_cast<const bf16x8*>(&B[mt * 16 + lr][kt * 32 + lg * 8]);
  for (int nt = 0; nt < 24; ++nt) {
    int col = nt * 16 + lr;
    float bb = bih[col] + (nt < 16 ? bhh[col] : 0.f);  // fold bhh into r/z gates
    #pragma unroll
    for (int mt = 0; mt < 2; ++mt) {
      f32x4 c = {0.f, 0.f, 0.f, 0.f};
      #pragma unroll
      for (int kt = 0; kt < 4; ++kt) {
        bf16x8 bv = *reinterpret_cast<const bf16x8*>(wih + (size_t)(nt * 16 + lr) * 128 + kt * 32 + lg * 8);
        c = __builtin_amdgcn_mfma_f32_16x16x32_bf16(ag[mt][kt], bv, c, 0, 0, 0);
      }
      #pragma unroll
      for (int r = 0; r < 4; ++r)
        gates[(size_t)(m0 + mt * 16 + lg * 4 + r) * 384 + col] = f2b(c[r] + bb);
    }
  }
}

// ---------------------------------------------------------------------------
// K2: x-path: obs(128) -> relu fc(128) -> relu fc(128) = x_embed (output 4)
// ---------------------------------------------------------------------------
__global__ __launch_bounds__(256) void k_xpath(
    const float* __restrict__ obs, const short* __restrict__ w1, const float* __restrict__ b1,
    const short* __restrict__ w2, const float* __restrict__ b2,
    float* __restrict__ xe)
{
  __shared__ short buf[4][32][144];
  const int tid = threadIdx.x, w = tid >> 6, l = tid & 63;
  const int lr = l & 15, lg = l >> 4;
  const int m0 = blockIdx.x * 128 + w * 32;
  short (* __restrict__ B)[144] = buf[w];

  #pragma unroll
  for (int it = 0; it < 16; ++it) {
    int idx = (it * 64 + l) * 4;
    int row = idx >> 7, col = idx & 127;
    float4 v = *reinterpret_cast<const float4*>(obs + (size_t)(m0 + row) * 128 + col);
    bf16x4 p; p[0] = f2b(v.x); p[1] = f2b(v.y); p[2] = f2b(v.z); p[3] = f2b(v.w);
    *reinterpret_cast<bf16x4*>(&B[row][col]) = p;
  }
  __syncthreads();

  f32x4 acc[2][8];
  bf16x8 a1f[2][4];
  #pragma unroll
  for (int mt = 0; mt < 2; ++mt)
    #pragma unroll
    for (int kt = 0; kt < 4; ++kt)
      a1f[mt][kt] = *reinterpret_cast<const bf16x8*>(&B[mt * 16 + lr][kt * 32 + lg * 8]);
  #pragma unroll
  for (int nt = 0; nt < 8; ++nt)
    #pragma unroll
    for (int mt = 0; mt < 2; ++mt) {
      f32x4 c = {0.f, 0.f, 0.f, 0.f};
      #pragma unroll
      for (int kt = 0; kt < 4; ++kt) {
        bf16x8 bv = *reinterpret_cast<const bf16x8*>(w1 + (size_t)(nt * 16 + lr) * 128 + kt * 32 + lg * 8);
        c = __builtin_amdgcn_mfma_f32_16x16x32_bf16(a1f[mt][kt], bv, c, 0, 0, 0);
      }
      acc[mt][nt] = c;
    }
  __syncthreads();
  #pragma unroll
  for (int nt = 0; nt < 8; ++nt) {
    float bb = b1[nt * 16 + lr];
    #pragma unroll
    for (int mt = 0; mt < 2; ++mt)
      #pragma unroll
      for (int r = 0; r < 4; ++r) {
        float v = acc[mt][nt][r] + bb;
        B[mt * 16 + lg * 4 + r][nt * 16 + lr] = f2b(v > 0.f ? v : 0.f);
      }
  }
  __syncthreads();

  bf16x8 a2f[2][4];
  #pragma unroll
  for (int mt = 0; mt < 2; ++mt)
    #pragma unroll
    for (int kt = 0; kt < 4; ++kt)
      a2f[mt][kt] = *reinterpret_cast<const bf16x8*>(&B[mt * 16 + lr][kt * 32 + lg * 8]);
  #pragma unroll
  for (int nt = 0; nt < 8; ++nt) {
    float bb = b2[nt * 16 + lr];
    #pragma unroll
    for (int mt = 0; mt < 2; ++mt) {
      f32x4 c = {0.f, 0.f, 0.f, 0.f};
      #pragma unroll
      for (int kt = 0; kt < 4; ++kt) {
        bf16x8 bv = *reinterpret_cast<const bf16x8*>(w2 + (size_t)(nt * 16 + lr) * 128 + kt * 32 + lg * 8);
        c = __builtin_amdgcn_mfma_f32_16x16x32_bf16(a2f[mt][kt], bv, c, 0, 0, 0);
      }
      #pragma unroll
      for (int r = 0; r < 4; ++r) {
        float v = c[r] + bb;
        xe[(size_t)(m0 + mt * 16 + lg * 4 + r) * 128 + nt * 16 + lr] = (v > 0.f ? v : 0.f);
      }
    }
  }
}

// ---------------------------------------------------------------------------
// K3: GRU scan, v4. 32 blocks x 512 threads; wave w owns h-cols [16w,16w+16).
// Raw rcp/exp2 transcendentals (no Newton), bhh folded into gates for r/z,
// gate prefetch ~2 steps ahead (reload just-consumed register set), one
// lgkmcnt(0)+s_barrier per step (global ops never drained in-loop).
// ---------------------------------------------------------------------------
__global__ __launch_bounds__(512) void k_gru(
    const short* __restrict__ gates, const short* __restrict__ whh,
    const float* __restrict__ bhh, float* __restrict__ hseq)
{
  __shared__ short hb[2][16][136];
  const int tid = threadIdx.x, w = tid >> 6, l = tid & 63;
  const int lr = l & 15, lg = l >> 4;
  const int m0 = blockIdx.x * 16;
  const int c = w * 16 + lr;  // this lane's h/gate column (0..127)

  bf16x8 bfr[3][4];
  #pragma unroll
  for (int g = 0; g < 3; ++g)
    #pragma unroll
    for (int kt = 0; kt < 4; ++kt)
      bfr[g][kt] = *reinterpret_cast<const bf16x8*>(whh + (size_t)(g * 128 + c) * 128 + kt * 32 + lg * 8);
  const float bbn = bhh[256 + c];  // only the n-gate bias survives (scaled by r)

  for (int i = tid; i < 16 * 136; i += 512) (&hb[0][0][0])[i] = 0;

  float hold[4] = {0.f, 0.f, 0.f, 0.f};

  unsigned gA[3][4], gB[3][4];
  #pragma unroll
  for (int g = 0; g < 3; ++g)
    #pragma unroll
    for (int r = 0; r < 4; ++r) {
      gA[g][r] = (unsigned short)gates[((size_t)(m0 + lg * 4 + r)) * 384 + g * 128 + c];
      gB[g][r] = (unsigned short)gates[((size_t)512 + m0 + lg * 4 + r) * 384 + g * 128 + c];
    }

  __syncthreads();

#define GRU_STEP(T, GC, BR, BW)                                                \
  {                                                                            \
    const int t_ = (T);                                                        \
    bf16x8 a_[4];                                                              \
    _Pragma("unroll")                                                          \
    for (int kt = 0; kt < 4; ++kt)                                             \
      a_[kt] = *reinterpret_cast<const bf16x8*>(&hb[BR][lr][kt * 32 + lg * 8]);\
    f32x4 acc_[3];                                                             \
    _Pragma("unroll")                                                          \
    for (int g = 0; g < 3; ++g) {                                              \
      f32x4 cc = {0.f, 0.f, 0.f, 0.f};                                         \
      _Pragma("unroll")                                                        \
      for (int kt = 0; kt < 4; ++kt)                                           \
        cc = __builtin_amdgcn_mfma_f32_16x16x32_bf16(a_[kt], bfr[g][kt], cc, 0, 0, 0); \
      acc_[g] = cc;                                                            \
    }                                                                          \
    float ho_[4];                                                              \
    _Pragma("unroll")                                                          \
    for (int r = 0; r < 4; ++r) {                                              \
      const int m = lg * 4 + r;                                                \
      float rr = sigm(u2f(GC[0][r]) + acc_[0][r]);                             \
      float zz = sigm(u2f(GC[1][r]) + acc_[1][r]);                             \
      float tt = u2f(GC[2][r]) + (acc_[2][r] + bbn) * rr;                      \
      float nn = 1.f - 2.f * rcpf(1.f + exp2f_(2.88539008f * tt));             \
      float ho = hold[r];                                                      \
      float hnew = nn + zz * (ho - nn);                                        \
      ho_[r] = ho;                                                             \
      hold[r] = hnew;                                                          \
      hb[BW][m][c] = f2b(hnew);                                                \
    }                                                                          \
    _Pragma("unroll")                                                          \
    for (int r = 0; r < 4; ++r)                                                \
      hseq[((size_t)t_ * 512 + m0 + lg * 4 + r) * 128 + c] = ho_[r];           \
    const int tp_ = (t_ + 2) & 255;                                            \
    _Pragma("unroll")                                                          \
    for (int g = 0; g < 3; ++g)                                                \
      _Pragma("unroll")                                                        \
      for (int r = 0; r < 4; ++r)                                              \
        GC[g][r] = (unsigned short)gates[((size_t)tp_ * 512 + m0 + lg * 4 + r) * 384 + g * 128 + c]; \
    asm volatile("s_waitcnt lgkmcnt(0)" ::: "memory");                         \
    __builtin_amdgcn_s_barrier();                                              \
    __builtin_amdgcn_sched_barrier(0);                                         \
  }

  for (int tt = 0; tt < 128; ++tt) {
    GRU_STEP(2 * tt,     gA, 0, 1)
    GRU_STEP(2 * tt + 1, gB, 1, 0)
  }
#undef GRU_STEP
}

// ---------------------------------------------------------------------------
// K4: posterior DBlock + reparam sample, v2. 64 rows, 512 threads (8 waves =
// 2 row-halves x 4 col-quarters). Single LDS buffer: t overlays bin
// (barrier-separated) -> 35 KB LDS -> 3-4 blocks/CU for latency hiding.
// ---------------------------------------------------------------------------
__global__ __launch_bounds__(512) void k_post(
    const float* __restrict__ xe, const float* __restrict__ hs, const float* __restrict__ eps,
    const short* __restrict__ pw1, const float* __restrict__ pb1,
    const short* __restrict__ pw2, const float* __restrict__ pb2,
    const short* __restrict__ pwmu, const float* __restrict__ pbmu,
    const short* __restrict__ pwls, const float* __restrict__ pbls,
    float* __restrict__ mu, float* __restrict__ ls, float* __restrict__ samp)
{
  __shared__ short bin[64][272];
  const int tid = threadIdx.x, w = tid >> 6, l = tid & 63;
  const int lr = l & 15, lg = l >> 4;
  const int p = w >> 2;   // row-half (0..1): rows [32p, 32p+32)
  const int q = w & 3;    // col-quarter (0..3)
  const int m0 = blockIdx.x * 64;

  // stage post_in = [x_embed | h_seq] 64 rows x 256 cols as bf16
  #pragma unroll
  for (int it = 0; it < 8; ++it) {
    int idx = (it * 512 + tid) * 4;
    int row = idx >> 8, col = idx & 255;
    const float* src = (col < 128) ? (xe + (size_t)(m0 + row) * 128 + col)
                                   : (hs + (size_t)(m0 + row) * 128 + (col - 128));
    float4 v = *reinterpret_cast<const float4*>(src);
    bf16x4 pk; pk[0] = f2b(v.x); pk[1] = f2b(v.y); pk[2] = f2b(v.z); pk[3] = f2b(v.w);
    *reinterpret_cast<bf16x4*>(&bin[row][col]) = pk;
  }
  __syncthreads();

  // fc1 (relu) * sigmoid(fc2): wave handles rows [32p,32p+32), cols [64q,64q+64)
  f32x4 a1[2][4], a2[2][4];
  #pragma unroll
  for (int mt = 0; mt < 2; ++mt)
    #pragma unroll
    for (int j = 0; j < 4; ++j) { a1[mt][j] = (f32x4){0.f,0.f,0.f,0.f}; a2[mt][j] = (f32x4){0.f,0.f,0.f,0.f}; }
  #pragma unroll
  for (int kt = 0; kt < 8; ++kt) {
    bf16x8 a[2];
    #pragma unroll
    for (int mt = 0; mt < 2; ++mt)
      a[mt] = *reinterpret_cast<const bf16x8*>(&bin[p * 32 + mt * 16 + lr][kt * 32 + lg * 8]);
    #pragma unroll
    for (int j = 0; j < 4; ++j) {
      int n = (4 * q + j) * 16 + lr;
      bf16x8 b1v = *reinterpret_cast<const bf16x8*>(pw1 + (size_t)n * 256 + kt * 32 + lg * 8);
      bf16x8 b2v = *reinterpret_cast<const bf16x8*>(pw2 + (size_t)n * 256 + kt * 32 + lg * 8);
      #pragma unroll
      for (int mt = 0; mt < 2; ++mt) {
        a1[mt][j] = __builtin_amdgcn_mfma_f32_16x16x32_bf16(a[mt], b1v, a1[mt][j], 0, 0, 0);
        a2[mt][j] = __builtin_amdgcn_mfma_f32_16x16x32_bf16(a[mt], b2v, a2[mt][j], 0, 0, 0);
      }
    }
  }
  __syncthreads();  // all fc1 reads of bin complete before t overlays it

  #pragma unroll
  for (int j = 0; j < 4; ++j) {
    int n = (4 * q + j) * 16 + lr;
    float bb1 = pb1[n], bb2 = pb2[n];
    #pragma unroll
    for (int mt = 0; mt < 2; ++mt)
      #pragma unroll
      for (int r = 0; r < 4; ++r) {
        float t1 = a1[mt][j][r] + bb1; t1 = t1 > 0.f ? t1 : 0.f;
        float t2 = sigm(a2[mt][j][r] + bb2);
        bin[p * 32 + mt * 16 + lg * 4 + r][n] = f2b(t1 * t2);
      }
  }
  __syncthreads();

  // mu/ls: wave handles rows [32p,32p+32), cols [32q,32q+32) of each
  f32x4 am[2][2], al[2][2];
  #pragma unroll
  for (int mt = 0; mt < 2; ++mt)
    #pragma unroll
    for (int j = 0; j < 2; ++j) { am[mt][j] = (f32x4){0.f,0.f,0.f,0.f}; al[mt][j] = (f32x4){0.f,0.f,0.f,0.f}; }
  #pragma unroll
  for (int kt = 0; kt < 8; ++kt) {
    bf16x8 a[2];
    #pragma unroll
    for (int mt = 0; mt < 2; ++mt)
      a[mt] = *reinterpret_cast<const bf16x8*>(&bin[p * 32 + mt * 16 + lr][kt * 32 + lg * 8]);
    #pragma unroll
    for (int j = 0; j < 2; ++j) {
      int n = q * 32 + j * 16 + lr;
      bf16x8 bm = *reinterpret_cast<const bf16x8*>(pwmu + (size_t)n * 256 + kt * 32 + lg * 8);
      bf16x8 bl = *reinterpret_cast<const bf16x8*>(pwls + (size_t)n * 256 + kt * 32 + lg * 8);
      #pragma unroll
      for (int mt = 0; mt < 2; ++mt) {
        am[mt][j] = __builtin_amdgcn_mfma_f32_16x16x32_bf16(a[mt], bm, am[mt][j], 0, 0, 0);
        al[mt][j] = __builtin_amdgcn_mfma_f32_16x16x32_bf16(a[mt], bl, al[mt][j], 0, 0, 0);
      }
    }
  }
  #pragma unroll
  for (int j = 0; j < 2; ++j) {
    int col = q * 32 + j * 16 + lr;
    float bm = pbmu[col], bl = pbls[col];
    #pragma unroll
    for (int mt = 0; mt < 2; ++mt)
      #pragma unroll
      for (int r = 0; r < 4; ++r) {
        size_t off = (size_t)(m0 + p * 32 + mt * 16 + lg * 4 + r) * 128 + col;
        float m_ = am[mt][j][r] + bm;
        float l_ = al[mt][j][r] + bl;
        mu[off] = m_;
        ls[off] = l_;
        samp[off] = m_ + exp2f_(1.44269504f * l_) * eps[off];
      }
  }
}

// ---------------------------------------------------------------------------
extern "C" void kernel_launch(void* const* d_in, const int* in_sizes, int n_in,
                              void* d_out, int out_size, void* d_ws, size_t ws_size,
                              hipStream_t stream) {
  const float* ext   = (const float*)d_in[0];
  const float* obs   = (const float*)d_in[1];
  const float* eps   = (const float*)d_in[2];
  const float* u_w1  = (const float*)d_in[3];
  const float* u_b1  = (const float*)d_in[4];
  const float* u_w2  = (const float*)d_in[5];
  const float* u_b2  = (const float*)d_in[6];
  const float* x_w1  = (const float*)d_in[7];
  const float* x_b1  = (const float*)d_in[8];
  const float* x_w2  = (const float*)d_in[9];
  const float* x_b2  = (const float*)d_in[10];
  const float* pw1   = (const float*)d_in[11];
  const float* pb1   = (const float*)d_in[12];
  const float* pw2   = (const float*)d_in[13];
  const float* pb2   = (const float*)d_in[14];
  const float* pwmu  = (const float*)d_in[15];
  const float* pbmu  = (const float*)d_in[16];
  const float* pwls  = (const float*)d_in[17];
  const float* pbls  = (const float*)d_in[18];
  const float* g_wih = (const float*)d_in[19];
  const float* g_whh = (const float*)d_in[20];
  const float* g_bih = (const float*)d_in[21];
  const float* g_bhh = (const float*)d_in[22];

  float* out = (float*)d_out;
  float* o_mu = out;
  float* o_ls = out + 16777216;
  float* o_sp = out + 33554432;
  float* o_hs = out + 50331648;
  float* o_xe = out + 67108864;
  // bf16 x_gates scratch (L*B*384 shorts = 100 MB) lives at the start of the
  // output region; fully consumed by k_gru before k_post overwrites it.
  short* gates = (short*)out;

  short* wb = (short*)d_ws;
  short* c_uw1  = wb + 0;
  short* c_uw2  = wb + 8192;
  short* c_xw1  = wb + 24576;
  short* c_xw2  = wb + 40960;
  short* c_wih  = wb + 57344;
  short* c_whh  = wb + 106496;
  short* c_pw1  = wb + 155648;
  short* c_pw2  = wb + 221184;
  short* c_pwmu = wb + 286720;
  short* c_pwls = wb + 319488;

  k_cvt<<<1376, 256, 0, stream>>>(u_w1, u_w2, x_w1, x_w2, g_wih, g_whh,
                                  pw1, pw2, pwmu, pwls, wb);
  k_upath<<<1024, 256, 0, stream>>>(ext, c_uw1, u_b1, c_uw2, u_b2, c_wih, g_bih, g_bhh, gates);
  k_xpath<<<1024, 256, 0, stream>>>(obs, c_xw1, x_b1, c_xw2, x_b2, o_xe);
  k_gru<<<32, 512, 0, stream>>>(gates, c_whh, g_bhh, o_hs);
  k_post<<<2048, 512, 0, stream>>>(o_xe, o_hs, eps, c_pw1, pb1, c_pw2, pb2,
                                   c_pwmu, pbmu, c_pwls, pbls, o_mu, o_ls, o_sp);
}

// Round 5
// 493.213 us; speedup vs baseline: 2.1950x; 1.2709x over previous
//
#include <hip/hip_runtime.h>

// ---------------------------------------------------------------------------
// VAERNN forward posterior, MI355X bf16-MFMA implementation.
// L=256 B=512 K=128 IN=64 STATE=128 OBS=128, LB = L*B = 131072 rows.
// ---------------------------------------------------------------------------

typedef __attribute__((ext_vector_type(8))) short bf16x8;
typedef __attribute__((ext_vector_type(4))) short bf16x4;
typedef __attribute__((ext_vector_type(4))) float f32x4;

#define LB 131072

__device__ __forceinline__ short f2b(float f) {
  union { float f; unsigned u; } v; v.f = f;
  unsigned r = (v.u + 0x7FFFu + ((v.u >> 16) & 1u)) >> 16;  // RNE
  return (short)r;
}
__device__ __forceinline__ float u2f(unsigned u) {
  union { unsigned u; float f; } v; v.u = u << 16; return v.f;
}
__device__ __forceinline__ float rcpf(float x) { return __builtin_amdgcn_rcpf(x); }
__device__ __forceinline__ float exp2f_(float x) { return __builtin_amdgcn_exp2f(x); }
__device__ __forceinline__ float sigm(float x) { return rcpf(1.f + exp2f_(-1.44269504f * x)); }

// lgkm-only barrier: LDS ordering without draining global loads/stores (T4).
#define LGKM_BAR()                                          \
  asm volatile("s_waitcnt lgkmcnt(0)" ::: "memory");        \
  __builtin_amdgcn_s_barrier();                             \
  __builtin_amdgcn_sched_barrier(0);

// ---------------------------------------------------------------------------
// K0: convert all weight matrices fp32 -> bf16 into workspace (contiguous).
// ---------------------------------------------------------------------------
__global__ __launch_bounds__(256) void k_cvt(
    const float* __restrict__ s0, const float* __restrict__ s1,
    const float* __restrict__ s2, const float* __restrict__ s3,
    const float* __restrict__ s4, const float* __restrict__ s5,
    const float* __restrict__ s6, const float* __restrict__ s7,
    const float* __restrict__ s8, const float* __restrict__ s9,
    short* __restrict__ dst)
{
  int i = blockIdx.x * 256 + threadIdx.x;
  if (i >= 352256) return;
  const float* src; int off;
  if      (i <   8192) { src = s0; off = i; }
  else if (i <  24576) { src = s1; off = i - 8192; }
  else if (i <  40960) { src = s2; off = i - 24576; }
  else if (i <  57344) { src = s3; off = i - 40960; }
  else if (i < 106496) { src = s4; off = i - 57344; }
  else if (i < 155648) { src = s5; off = i - 106496; }
  else if (i < 221184) { src = s6; off = i - 155648; }
  else if (i < 286720) { src = s7; off = i - 221184; }
  else if (i < 319488) { src = s8; off = i - 286720; }
  else                 { src = s9; off = i - 319488; }
  dst[i] = f2b(src[off]);
}

// ---------------------------------------------------------------------------
// K1: u-path: x(64) -> relu fc(128) -> relu fc(128) -> gates GEMM (384).
// Wave-private LDS tile => NO barriers (same-wave DS ops are in-order).
// Writes x_gates bf16 with bih (+bhh for r/z) folded in.
// ---------------------------------------------------------------------------
__global__ __launch_bounds__(256) void k_upath(
    const float* __restrict__ x, const short* __restrict__ w1, const float* __restrict__ b1,
    const short* __restrict__ w2, const float* __restrict__ b2,
    const short* __restrict__ wih, const float* __restrict__ bih,
    const float* __restrict__ bhh,
    short* __restrict__ gates)
{
  __shared__ short buf[4][32][144];
  const int tid = threadIdx.x, w = tid >> 6, l = tid & 63;
  const int lr = l & 15, lg = l >> 4;
  const int m0 = blockIdx.x * 128 + w * 32;
  short (* __restrict__ B)[144] = buf[w];

  #pragma unroll
  for (int it = 0; it < 8; ++it) {
    int idx = (it * 64 + l) * 4;
    int row = idx >> 6, col = idx & 63;
    float4 v = *reinterpret_cast<const float4*>(x + (size_t)(m0 + row) * 64 + col);
    bf16x4 p; p[0] = f2b(v.x); p[1] = f2b(v.y); p[2] = f2b(v.z); p[3] = f2b(v.w);
    *reinterpret_cast<bf16x4*>(&B[row][col]) = p;
  }

  f32x4 acc[2][8];

  // layer1: K=64 -> N=128
  {
    bf16x8 a[2][2];
    #pragma unroll
    for (int mt = 0; mt < 2; ++mt)
      #pragma unroll
      for (int kt = 0; kt < 2; ++kt)
        a[mt][kt] = *reinterpret_cast<const bf16x8*>(&B[mt * 16 + lr][kt * 32 + lg * 8]);
    #pragma unroll
    for (int nt = 0; nt < 8; ++nt)
      #pragma unroll
      for (int mt = 0; mt < 2; ++mt) {
        f32x4 c = {0.f, 0.f, 0.f, 0.f};
        #pragma unroll
        for (int kt = 0; kt < 2; ++kt) {
          bf16x8 bv = *reinterpret_cast<const bf16x8*>(w1 + (size_t)(nt * 16 + lr) * 64 + kt * 32 + lg * 8);
          c = __builtin_amdgcn_mfma_f32_16x16x32_bf16(a[mt][kt], bv, c, 0, 0, 0);
        }
        acc[mt][nt] = c;
      }
  }
  #pragma unroll
  for (int nt = 0; nt < 8; ++nt) {
    float bb = b1[nt * 16 + lr];
    #pragma unroll
    for (int mt = 0; mt < 2; ++mt)
      #pragma unroll
      for (int r = 0; r < 4; ++r) {
        float v = acc[mt][nt][r] + bb;
        B[mt * 16 + lg * 4 + r][nt * 16 + lr] = f2b(v > 0.f ? v : 0.f);
      }
  }

  // layer2: K=128 -> N=128 (u_embed)
  bf16x8 a2f[2][4];
  #pragma unroll
  for (int mt = 0; mt < 2; ++mt)
    #pragma unroll
    for (int kt = 0; kt < 4; ++kt)
      a2f[mt][kt] = *reinterpret_cast<const bf16x8*>(&B[mt * 16 + lr][kt * 32 + lg * 8]);
  #pragma unroll
  for (int nt = 0; nt < 8; ++nt)
    #pragma unroll
    for (int mt = 0; mt < 2; ++mt) {
      f32x4 c = {0.f, 0.f, 0.f, 0.f};
      #pragma unroll
      for (int kt = 0; kt < 4; ++kt) {
        bf16x8 bv = *reinterpret_cast<const bf16x8*>(w2 + (size_t)(nt * 16 + lr) * 128 + kt * 32 + lg * 8);
        c = __builtin_amdgcn_mfma_f32_16x16x32_bf16(a2f[mt][kt], bv, c, 0, 0, 0);
      }
      acc[mt][nt] = c;
    }
  #pragma unroll
  for (int nt = 0; nt < 8; ++nt) {
    float bb = b2[nt * 16 + lr];
    #pragma unroll
    for (int mt = 0; mt < 2; ++mt)
      #pragma unroll
      for (int r = 0; r < 4; ++r) {
        float v = acc[mt][nt][r] + bb;
        B[mt * 16 + lg * 4 + r][nt * 16 + lr] = f2b(v > 0.f ? v : 0.f);
      }
  }

  // gates: K=128 -> N=384, streamed per N-tile, written bf16 with fused bias
  bf16x8 ag[2][4];
  #pragma unroll
  for (int mt = 0; mt < 2; ++mt)
    #pragma unroll
    for (int kt = 0; kt < 4; ++kt)
      ag[mt][kt] = *reinterpret_cast<const bf16x8*>(&B[mt * 16 + lr][kt * 32 + lg * 8]);
  for (int nt = 0; nt < 24; ++nt) {
    int col = nt * 16 + lr;
    float bb = bih[col] + (nt < 16 ? bhh[col] : 0.f);  // fold bhh into r/z gates
    #pragma unroll
    for (int mt = 0; mt < 2; ++mt) {
      f32x4 c = {0.f, 0.f, 0.f, 0.f};
      #pragma unroll
      for (int kt = 0; kt < 4; ++kt) {
        bf16x8 bv = *reinterpret_cast<const bf16x8*>(wih + (size_t)(nt * 16 + lr) * 128 + kt * 32 + lg * 8);
        c = __builtin_amdgcn_mfma_f32_16x16x32_bf16(ag[mt][kt], bv, c, 0, 0, 0);
      }
      #pragma unroll
      for (int r = 0; r < 4; ++r)
        gates[(size_t)(m0 + mt * 16 + lg * 4 + r) * 384 + col] = f2b(c[r] + bb);
    }
  }
}

// ---------------------------------------------------------------------------
// K2: fused GRU scan + x-path (heterogeneous blocks).
// Blocks 0..31: GRU scan (serial, 32 CUs). Blocks 32..543: x-path embedding
// (fills the other 224 CUs "for free" while the GRU runs).
// x-path waves are fully independent (wave-private LDS, no barriers).
// ---------------------------------------------------------------------------
__global__ __launch_bounds__(512) void k_grux(
    const short* __restrict__ gates, const short* __restrict__ whh,
    const float* __restrict__ bhh, float* __restrict__ hseq,
    const float* __restrict__ obs, const short* __restrict__ xw1,
    const float* __restrict__ xb1, const short* __restrict__ xw2,
    const float* __restrict__ xb2, float* __restrict__ xe)
{
  __shared__ short smem_[8 * 32 * 136];   // union: gru hb[2][16][136] | xpath 8x[32][136]
  const int tid = threadIdx.x, w = tid >> 6, l = tid & 63;
  const int lr = l & 15, lg = l >> 4;

  if (blockIdx.x < 32) {
    // ---------------- GRU path ----------------
    short (*hb)[16][136] = reinterpret_cast<short (*)[16][136]>(smem_);
    const int m0 = blockIdx.x * 16;
    const int c = w * 16 + lr;  // this lane's h/gate column (0..127)

    bf16x8 bfr[3][4];
    #pragma unroll
    for (int g = 0; g < 3; ++g)
      #pragma unroll
      for (int kt = 0; kt < 4; ++kt)
        bfr[g][kt] = *reinterpret_cast<const bf16x8*>(whh + (size_t)(g * 128 + c) * 128 + kt * 32 + lg * 8);
    const float bbn = bhh[256 + c];  // only n-gate bias survives (scaled by r)

    for (int i = tid; i < 2 * 16 * 136; i += 512) smem_[i] = 0;

    float hold[4] = {0.f, 0.f, 0.f, 0.f};

    unsigned gA[3][4], gB[3][4];
    #pragma unroll
    for (int g = 0; g < 3; ++g)
      #pragma unroll
      for (int r = 0; r < 4; ++r) {
        gA[g][r] = (unsigned short)gates[((size_t)(m0 + lg * 4 + r)) * 384 + g * 128 + c];
        gB[g][r] = (unsigned short)gates[((size_t)512 + m0 + lg * 4 + r) * 384 + g * 128 + c];
      }

    __syncthreads();

#define GRU_STEP(T, GC, BR, BW)                                                \
  {                                                                            \
    const int t_ = (T);                                                        \
    bf16x8 a_[4];                                                              \
    _Pragma("unroll")                                                          \
    for (int kt = 0; kt < 4; ++kt)                                             \
      a_[kt] = *reinterpret_cast<const bf16x8*>(&hb[BR][lr][kt * 32 + lg * 8]);\
    f32x4 acc_[3];                                                             \
    _Pragma("unroll")                                                          \
    for (int g = 0; g < 3; ++g) {                                              \
      f32x4 cc = {0.f, 0.f, 0.f, 0.f};                                         \
      _Pragma("unroll")                                                        \
      for (int kt = 0; kt < 4; ++kt)                                           \
        cc = __builtin_amdgcn_mfma_f32_16x16x32_bf16(a_[kt], bfr[g][kt], cc, 0, 0, 0); \
      acc_[g] = cc;                                                            \
    }                                                                          \
    float ho_[4];                                                              \
    _Pragma("unroll")                                                          \
    for (int r = 0; r < 4; ++r) {                                              \
      const int m = lg * 4 + r;                                                \
      float rr = sigm(u2f(GC[0][r]) + acc_[0][r]);                             \
      float zz = sigm(u2f(GC[1][r]) + acc_[1][r]);                             \
      float tt = u2f(GC[2][r]) + (acc_[2][r] + bbn) * rr;                      \
      float nn = 1.f - 2.f * rcpf(1.f + exp2f_(2.88539008f * tt));             \
      float ho = hold[r];                                                      \
      float hnew = nn + zz * (ho - nn);                                        \
      ho_[r] = ho;                                                             \
      hold[r] = hnew;                                                          \
      hb[BW][m][c] = f2b(hnew);                                                \
    }                                                                          \
    _Pragma("unroll")                                                          \
    for (int r = 0; r < 4; ++r)                                                \
      hseq[((size_t)t_ * 512 + m0 + lg * 4 + r) * 128 + c] = ho_[r];           \
    const int tp_ = (t_ + 2) & 255;                                            \
    _Pragma("unroll")                                                          \
    for (int g = 0; g < 3; ++g)                                                \
      _Pragma("unroll")                                                        \
      for (int r = 0; r < 4; ++r)                                              \
        GC[g][r] = (unsigned short)gates[((size_t)tp_ * 512 + m0 + lg * 4 + r) * 384 + g * 128 + c]; \
    asm volatile("s_waitcnt lgkmcnt(0)" ::: "memory");                         \
    __builtin_amdgcn_s_barrier();                                              \
    __builtin_amdgcn_sched_barrier(0);                                         \
  }

    for (int tt = 0; tt < 128; ++tt) {
      GRU_STEP(2 * tt,     gA, 0, 1)
      GRU_STEP(2 * tt + 1, gB, 1, 0)
    }
#undef GRU_STEP
  } else {
    // ---------------- x-path (obs -> relu fc -> relu fc = x_embed) ----------
    const int m0 = (blockIdx.x - 32) * 256 + w * 32;
    short (* __restrict__ B)[136] = reinterpret_cast<short (*)[136]>(&smem_[w * 32 * 136]);

    #pragma unroll
    for (int it = 0; it < 16; ++it) {
      int idx = (it * 64 + l) * 4;
      int row = idx >> 7, col = idx & 127;
      float4 v = *reinterpret_cast<const float4*>(obs + (size_t)(m0 + row) * 128 + col);
      bf16x4 p; p[0] = f2b(v.x); p[1] = f2b(v.y); p[2] = f2b(v.z); p[3] = f2b(v.w);
      *reinterpret_cast<bf16x4*>(&B[row][col]) = p;
    }

    f32x4 acc[2][8];
    bf16x8 a1f[2][4];
    #pragma unroll
    for (int mt = 0; mt < 2; ++mt)
      #pragma unroll
      for (int kt = 0; kt < 4; ++kt)
        a1f[mt][kt] = *reinterpret_cast<const bf16x8*>(&B[mt * 16 + lr][kt * 32 + lg * 8]);
    #pragma unroll
    for (int nt = 0; nt < 8; ++nt)
      #pragma unroll
      for (int mt = 0; mt < 2; ++mt) {
        f32x4 c = {0.f, 0.f, 0.f, 0.f};
        #pragma unroll
        for (int kt = 0; kt < 4; ++kt) {
          bf16x8 bv = *reinterpret_cast<const bf16x8*>(xw1 + (size_t)(nt * 16 + lr) * 128 + kt * 32 + lg * 8);
          c = __builtin_amdgcn_mfma_f32_16x16x32_bf16(a1f[mt][kt], bv, c, 0, 0, 0);
        }
        acc[mt][nt] = c;
      }
    #pragma unroll
    for (int nt = 0; nt < 8; ++nt) {
      float bb = xb1[nt * 16 + lr];
      #pragma unroll
      for (int mt = 0; mt < 2; ++mt)
        #pragma unroll
        for (int r = 0; r < 4; ++r) {
          float v = acc[mt][nt][r] + bb;
          B[mt * 16 + lg * 4 + r][nt * 16 + lr] = f2b(v > 0.f ? v : 0.f);
        }
    }

    bf16x8 a2f[2][4];
    #pragma unroll
    for (int mt = 0; mt < 2; ++mt)
      #pragma unroll
      for (int kt = 0; kt < 4; ++kt)
        a2f[mt][kt] = *reinterpret_cast<const bf16x8*>(&B[mt * 16 + lr][kt * 32 + lg * 8]);
    #pragma unroll
    for (int nt = 0; nt < 8; ++nt) {
      float bb = xb2[nt * 16 + lr];
      #pragma unroll
      for (int mt = 0; mt < 2; ++mt) {
        f32x4 c = {0.f, 0.f, 0.f, 0.f};
        #pragma unroll
        for (int kt = 0; kt < 4; ++kt) {
          bf16x8 bv = *reinterpret_cast<const bf16x8*>(xw2 + (size_t)(nt * 16 + lr) * 128 + kt * 32 + lg * 8);
          c = __builtin_amdgcn_mfma_f32_16x16x32_bf16(a2f[mt][kt], bv, c, 0, 0, 0);
        }
        #pragma unroll
        for (int r = 0; r < 4; ++r) {
          float v = c[r] + bb;
          xe[(size_t)(m0 + mt * 16 + lg * 4 + r) * 128 + nt * 16 + lr] = (v > 0.f ? v : 0.f);
        }
      }
    }
  }
}

// ---------------------------------------------------------------------------
// K4: posterior DBlock + reparam, v3. 512 blocks x 512 thr, grid-stride over
// 8 tiles of 32 rows. fc1 weight frags REGISTER-RESIDENT across tiles; fc2 and
// mu/ls frags re-streamed from L2 per tile (anti-LICM asm keeps them
// transient). A staged once in LDS; t overlays A. lgkm-only barriers.
// ---------------------------------------------------------------------------
#define PT 8
__global__ __launch_bounds__(512) void k_post(
    const float* __restrict__ xe, const float* __restrict__ hs, const float* __restrict__ eps,
    const short* __restrict__ pw1, const float* __restrict__ pb1,
    const short* __restrict__ pw2, const float* __restrict__ pb2,
    const short* __restrict__ pwmu, const float* __restrict__ pbmu,
    const short* __restrict__ pwls, const float* __restrict__ pbls,
    float* __restrict__ mu, float* __restrict__ ls, float* __restrict__ samp)
{
  __shared__ short Ab[32][264];
  const int tid = threadIdx.x, w = tid >> 6, l = tid & 63;
  const int lr = l & 15, lg = l >> 4;
  const int srow = tid >> 4, scol = (tid & 15) * 8;
  const int n2 = w * 16 + lr;           // ph2 output column (mu & ls)

  // fc1 weights resident: cols n = w*32 + j*16 + lr
  bf16x8 wf1[2][8];
  float bb1[2], bb2[2];
  #pragma unroll
  for (int j = 0; j < 2; ++j) {
    const int n = w * 32 + j * 16 + lr;
    bb1[j] = pb1[n]; bb2[j] = pb2[n];
    #pragma unroll
    for (int kt = 0; kt < 8; ++kt)
      wf1[j][kt] = *reinterpret_cast<const bf16x8*>(pw1 + (size_t)n * 256 + kt * 32 + lg * 8);
  }
  const float bbm = pbmu[n2], bbl = pbls[n2];

  for (int it = 0; it < PT; ++it) {
    const size_t m0 = ((size_t)blockIdx.x * PT + it) * 32;

    // anti-LICM: make streamed weight bases iteration-dependent opaque values
    unsigned long long a2 = (unsigned long long)pw2;
    unsigned long long am_ = (unsigned long long)pwmu;
    unsigned long long al_ = (unsigned long long)pwls;
    asm volatile("" : "+s"(a2), "+s"(am_), "+s"(al_));
    const short* pw2v = (const short*)a2;
    const short* pwmv = (const short*)am_;
    const short* pwlv = (const short*)al_;

    // eps prefetch for this tile
    float ev[2][4];
    #pragma unroll
    for (int mt = 0; mt < 2; ++mt)
      #pragma unroll
      for (int r = 0; r < 4; ++r)
        ev[mt][r] = eps[(m0 + mt * 16 + lg * 4 + r) * 128 + n2];

    // stage A = [xe | hs] rows m0..m0+31 as bf16
    {
      const float* px = xe + (m0 + srow) * 128 + scol;
      float4 v0 = *reinterpret_cast<const float4*>(px);
      float4 v1 = *reinterpret_cast<const float4*>(px + 4);
      bf16x8 pk;
      pk[0] = f2b(v0.x); pk[1] = f2b(v0.y); pk[2] = f2b(v0.z); pk[3] = f2b(v0.w);
      pk[4] = f2b(v1.x); pk[5] = f2b(v1.y); pk[6] = f2b(v1.z); pk[7] = f2b(v1.w);
      *reinterpret_cast<bf16x8*>(&Ab[srow][scol]) = pk;
      const float* ph = hs + (m0 + srow) * 128 + scol;
      float4 h0 = *reinterpret_cast<const float4*>(ph);
      float4 h1 = *reinterpret_cast<const float4*>(ph + 4);
      bf16x8 qk;
      qk[0] = f2b(h0.x); qk[1] = f2b(h0.y); qk[2] = f2b(h0.z); qk[3] = f2b(h0.w);
      qk[4] = f2b(h1.x); qk[5] = f2b(h1.y); qk[6] = f2b(h1.z); qk[7] = f2b(h1.w);
      *reinterpret_cast<bf16x8*>(&Ab[srow][128 + scol]) = qk;
    }
    LGKM_BAR();  // b1: A staged

    // ph1: t_pre = A @ {w1,w2}^T  (fc2 streamed)
    bf16x8 wf2[2][8];
    #pragma unroll
    for (int j = 0; j < 2; ++j) {
      const int n = w * 32 + j * 16 + lr;
      #pragma unroll
      for (int kt = 0; kt < 8; ++kt)
        wf2[j][kt] = *reinterpret_cast<const bf16x8*>(pw2v + (size_t)n * 256 + kt * 32 + lg * 8);
    }
    f32x4 ac1[2][2], ac2[2][2];  // [j][mt]
    #pragma unroll
    for (int j = 0; j < 2; ++j)
      #pragma unroll
      for (int mt = 0; mt < 2; ++mt) { ac1[j][mt] = (f32x4){0.f,0.f,0.f,0.f}; ac2[j][mt] = (f32x4){0.f,0.f,0.f,0.f}; }
    #pragma unroll
    for (int kt = 0; kt < 8; ++kt) {
      bf16x8 af[2];
      #pragma unroll
      for (int mt = 0; mt < 2; ++mt)
        af[mt] = *reinterpret_cast<const bf16x8*>(&Ab[mt * 16 + lr][kt * 32 + lg * 8]);
      #pragma unroll
      for (int j = 0; j < 2; ++j)
        #pragma unroll
        for (int mt = 0; mt < 2; ++mt) {
          ac1[j][mt] = __builtin_amdgcn_mfma_f32_16x16x32_bf16(af[mt], wf1[j][kt], ac1[j][mt], 0, 0, 0);
          ac2[j][mt] = __builtin_amdgcn_mfma_f32_16x16x32_bf16(af[mt], wf2[j][kt], ac2[j][mt], 0, 0, 0);
        }
    }

    // stream ph2 weights while ph1 finishes
    bf16x8 wm[8], wl[8];
    #pragma unroll
    for (int kt = 0; kt < 8; ++kt) {
      wm[kt] = *reinterpret_cast<const bf16x8*>(pwmv + (size_t)n2 * 256 + kt * 32 + lg * 8);
      wl[kt] = *reinterpret_cast<const bf16x8*>(pwlv + (size_t)n2 * 256 + kt * 32 + lg * 8);
    }
    LGKM_BAR();  // b2: all A reads done; t may overlay

    #pragma unroll
    for (int j = 0; j < 2; ++j)
      #pragma unroll
      for (int mt = 0; mt < 2; ++mt)
        #pragma unroll
        for (int r = 0; r < 4; ++r) {
          float t1 = ac1[j][mt][r] + bb1[j]; t1 = t1 > 0.f ? t1 : 0.f;
          float t2 = sigm(ac2[j][mt][r] + bb2[j]);
          Ab[mt * 16 + lg * 4 + r][w * 32 + j * 16 + lr] = f2b(t1 * t2);
        }
    LGKM_BAR();  // b3: t ready

    // ph2: mu/ls = t @ {wmu,wls}^T + reparam sample
    f32x4 amc[2], alc[2];
    #pragma unroll
    for (int mt = 0; mt < 2; ++mt) { amc[mt] = (f32x4){0.f,0.f,0.f,0.f}; alc[mt] = (f32x4){0.f,0.f,0.f,0.f}; }
    #pragma unroll
    for (int kt = 0; kt < 8; ++kt) {
      bf16x8 at[2];
      #pragma unroll
      for (int mt = 0; mt < 2; ++mt)
        at[mt] = *reinterpret_cast<const bf16x8*>(&Ab[mt * 16 + lr][kt * 32 + lg * 8]);
      #pragma unroll
      for (int mt = 0; mt < 2; ++mt) {
        amc[mt] = __builtin_amdgcn_mfma_f32_16x16x32_bf16(at[mt], wm[kt], amc[mt], 0, 0, 0);
        alc[mt] = __builtin_amdgcn_mfma_f32_16x16x32_bf16(at[mt], wl[kt], alc[mt], 0, 0, 0);
      }
    }
    #pragma unroll
    for (int mt = 0; mt < 2; ++mt)
      #pragma unroll
      for (int r = 0; r < 4; ++r) {
        size_t off = (m0 + mt * 16 + lg * 4 + r) * 128 + n2;
        float m_ = amc[mt][r] + bbm;
        float l_ = alc[mt][r] + bbl;
        mu[off] = m_;
        ls[off] = l_;
        samp[off] = m_ + exp2f_(1.44269504f * l_) * ev[mt][r];
      }
    LGKM_BAR();  // b4: t consumed before next tile's stage overwrites
  }
}

// ---------------------------------------------------------------------------
extern "C" void kernel_launch(void* const* d_in, const int* in_sizes, int n_in,
                              void* d_out, int out_size, void* d_ws, size_t ws_size,
                              hipStream_t stream) {
  const float* ext   = (const float*)d_in[0];
  const float* obs   = (const float*)d_in[1];
  const float* eps   = (const float*)d_in[2];
  const float* u_w1  = (const float*)d_in[3];
  const float* u_b1  = (const float*)d_in[4];
  const float* u_w2  = (const float*)d_in[5];
  const float* u_b2  = (const float*)d_in[6];
  const float* x_w1  = (const float*)d_in[7];
  const float* x_b1  = (const float*)d_in[8];
  const float* x_w2  = (const float*)d_in[9];
  const float* x_b2  = (const float*)d_in[10];
  const float* pw1   = (const float*)d_in[11];
  const float* pb1   = (const float*)d_in[12];
  const float* pw2   = (const float*)d_in[13];
  const float* pb2   = (const float*)d_in[14];
  const float* pwmu  = (const float*)d_in[15];
  const float* pbmu  = (const float*)d_in[16];
  const float* pwls  = (const float*)d_in[17];
  const float* pbls  = (const float*)d_in[18];
  const float* g_wih = (const float*)d_in[19];
  const float* g_whh = (const float*)d_in[20];
  const float* g_bih = (const float*)d_in[21];
  const float* g_bhh = (const float*)d_in[22];

  float* out = (float*)d_out;
  float* o_mu = out;
  float* o_ls = out + 16777216;
  float* o_sp = out + 33554432;
  float* o_hs = out + 50331648;
  float* o_xe = out + 67108864;
  // bf16 x_gates scratch (L*B*384 shorts = 100 MB) lives at the start of the
  // output region; fully consumed by k_grux before k_post overwrites it.
  short* gates = (short*)out;

  short* wb = (short*)d_ws;
  short* c_uw1  = wb + 0;
  short* c_uw2  = wb + 8192;
  short* c_xw1  = wb + 24576;
  short* c_xw2  = wb + 40960;
  short* c_wih  = wb + 57344;
  short* c_whh  = wb + 106496;
  short* c_pw1  = wb + 155648;
  short* c_pw2  = wb + 221184;
  short* c_pwmu = wb + 286720;
  short* c_pwls = wb + 319488;

  k_cvt<<<1376, 256, 0, stream>>>(u_w1, u_w2, x_w1, x_w2, g_wih, g_whh,
                                  pw1, pw2, pwmu, pwls, wb);
  k_upath<<<1024, 256, 0, stream>>>(ext, c_uw1, u_b1, c_uw2, u_b2, c_wih, g_bih, g_bhh, gates);
  k_grux<<<544, 512, 0, stream>>>(gates, c_whh, g_bhh, o_hs,
                                  obs, c_xw1, x_b1, c_xw2, x_b2, o_xe);
  k_post<<<512, 512, 0, stream>>>(o_xe, o_hs, eps, c_pw1, pb1, c_pw2, pb2,
                                  c_pwmu, pbmu, c_pwls, pbls, o_mu, o_ls, o_sp);
}

// Round 6
// 421.197 us; speedup vs baseline: 2.5703x; 1.1710x over previous
//
#include <hip/hip_runtime.h>

// ---------------------------------------------------------------------------
// VAERNN forward posterior, MI355X bf16-MFMA implementation.
// L=256 B=512 K=128 IN=64 STATE=128 OBS=128, LB = L*B = 131072 rows.
// ---------------------------------------------------------------------------

typedef __attribute__((ext_vector_type(8))) short bf16x8;
typedef __attribute__((ext_vector_type(4))) short bf16x4;
typedef __attribute__((ext_vector_type(4))) float f32x4;

#define LB 131072

__device__ __forceinline__ short f2b(float f) {
  union { float f; unsigned u; } v; v.f = f;
  unsigned r = (v.u + 0x7FFFu + ((v.u >> 16) & 1u)) >> 16;  // RNE
  return (short)r;
}
__device__ __forceinline__ float u2f(unsigned u) {
  union { unsigned u; float f; } v; v.u = u << 16; return v.f;
}
__device__ __forceinline__ float rcpf(float x) { return __builtin_amdgcn_rcpf(x); }
__device__ __forceinline__ float exp2f_(float x) { return __builtin_amdgcn_exp2f(x); }
__device__ __forceinline__ float sigm(float x) { return rcpf(1.f + exp2f_(-1.44269504f * x)); }

// lgkm-only barrier: LDS ordering without draining global loads/stores (T4).
#define LGKM_BAR()                                          \
  asm volatile("s_waitcnt lgkmcnt(0)" ::: "memory");        \
  __builtin_amdgcn_s_barrier();                             \
  __builtin_amdgcn_sched_barrier(0);

// ---------------------------------------------------------------------------
// K0: convert all weight matrices fp32 -> bf16 into workspace (contiguous).
// ---------------------------------------------------------------------------
__global__ __launch_bounds__(256) void k_cvt(
    const float* __restrict__ s0, const float* __restrict__ s1,
    const float* __restrict__ s2, const float* __restrict__ s3,
    const float* __restrict__ s4, const float* __restrict__ s5,
    const float* __restrict__ s6, const float* __restrict__ s7,
    const float* __restrict__ s8, const float* __restrict__ s9,
    short* __restrict__ dst)
{
  int i = blockIdx.x * 256 + threadIdx.x;
  if (i >= 352256) return;
  const float* src; int off;
  if      (i <   8192) { src = s0; off = i; }
  else if (i <  24576) { src = s1; off = i - 8192; }
  else if (i <  40960) { src = s2; off = i - 24576; }
  else if (i <  57344) { src = s3; off = i - 40960; }
  else if (i < 106496) { src = s4; off = i - 57344; }
  else if (i < 155648) { src = s5; off = i - 106496; }
  else if (i < 221184) { src = s6; off = i - 155648; }
  else if (i < 286720) { src = s7; off = i - 221184; }
  else if (i < 319488) { src = s8; off = i - 286720; }
  else                 { src = s9; off = i - 319488; }
  dst[i] = f2b(src[off]);
}

// ---------------------------------------------------------------------------
// K1: u-path v2: x(64) -> relu fc(128) -> relu fc(128) -> gates(384).
// 512 blocks x 512 thr, grid-stride 8 tiles of 32 rows. ALL weights
// register-resident (72 VGPR): w1/w2 col n1=16w+lr, wih cols 48w+16j+lr.
// Layer outputs exchanged via LDS; gates written back through LDS for
// vectorized (48B/lane) coalesced global stores. lgkm-only barriers.
// ---------------------------------------------------------------------------
#define UT 8
__global__ __launch_bounds__(512) void k_upath(
    const float* __restrict__ x, const short* __restrict__ w1, const float* __restrict__ b1,
    const short* __restrict__ w2, const float* __restrict__ b2,
    const short* __restrict__ wih, const float* __restrict__ bih,
    const float* __restrict__ bhh,
    short* __restrict__ gates)
{
  __shared__ short Xb[32][72];
  __shared__ short Tb[32][136];
  __shared__ short Gb[32][392];
  const int tid = threadIdx.x, w = tid >> 6, l = tid & 63;
  const int lr = l & 15, lg = l >> 4;
  const int n1 = w * 16 + lr;   // this lane's layer1/layer2 output column

  bf16x8 wf1[2], wf2[4], wfg[3][4];
  #pragma unroll
  for (int kt = 0; kt < 2; ++kt)
    wf1[kt] = *reinterpret_cast<const bf16x8*>(w1 + (size_t)n1 * 64 + kt * 32 + lg * 8);
  #pragma unroll
  for (int kt = 0; kt < 4; ++kt)
    wf2[kt] = *reinterpret_cast<const bf16x8*>(w2 + (size_t)n1 * 128 + kt * 32 + lg * 8);
  float bgv[3];
  #pragma unroll
  for (int j = 0; j < 3; ++j) {
    const int cg = w * 48 + j * 16 + lr;
    bgv[j] = bih[cg] + (cg < 256 ? bhh[cg] : 0.f);  // fold bhh into r/z gates
    #pragma unroll
    for (int kt = 0; kt < 4; ++kt)
      wfg[j][kt] = *reinterpret_cast<const bf16x8*>(wih + (size_t)cg * 128 + kt * 32 + lg * 8);
  }
  const float b1v = b1[n1], b2v = b2[n1];
  const int srow = tid >> 4, scol4 = (tid & 15) * 4, gcol = (tid & 15) * 24;

  for (int it = 0; it < UT; ++it) {
    const size_t m0 = ((size_t)blockIdx.x * UT + it) * 32;

    // stage x (32 x 64) as bf16
    {
      float4 v = *reinterpret_cast<const float4*>(x + (m0 + srow) * 64 + scol4);
      bf16x4 p; p[0] = f2b(v.x); p[1] = f2b(v.y); p[2] = f2b(v.z); p[3] = f2b(v.w);
      *reinterpret_cast<bf16x4*>(&Xb[srow][scol4]) = p;
    }
    LGKM_BAR();  // b1: x staged (also drains prev tile's Gb readback reads)

    // layer1: K=64 -> 16 cols/wave
    f32x4 a1c[2] = {(f32x4){0.f,0.f,0.f,0.f}, (f32x4){0.f,0.f,0.f,0.f}};
    #pragma unroll
    for (int kt = 0; kt < 2; ++kt) {
      #pragma unroll
      for (int mt = 0; mt < 2; ++mt) {
        bf16x8 af = *reinterpret_cast<const bf16x8*>(&Xb[mt * 16 + lr][kt * 32 + lg * 8]);
        a1c[mt] = __builtin_amdgcn_mfma_f32_16x16x32_bf16(af, wf1[kt], a1c[mt], 0, 0, 0);
      }
    }
    #pragma unroll
    for (int mt = 0; mt < 2; ++mt)
      #pragma unroll
      for (int r = 0; r < 4; ++r) {
        float v = a1c[mt][r] + b1v;
        Tb[mt * 16 + lg * 4 + r][n1] = f2b(v > 0.f ? v : 0.f);
      }
    LGKM_BAR();  // b2: layer1 exchanged

    // layer2: K=128 -> 16 cols/wave; output exchanged via Gb[.][0..127]
    f32x4 a2c[2] = {(f32x4){0.f,0.f,0.f,0.f}, (f32x4){0.f,0.f,0.f,0.f}};
    #pragma unroll
    for (int kt = 0; kt < 4; ++kt) {
      #pragma unroll
      for (int mt = 0; mt < 2; ++mt) {
        bf16x8 af = *reinterpret_cast<const bf16x8*>(&Tb[mt * 16 + lr][kt * 32 + lg * 8]);
        a2c[mt] = __builtin_amdgcn_mfma_f32_16x16x32_bf16(af, wf2[kt], a2c[mt], 0, 0, 0);
      }
    }
    #pragma unroll
    for (int mt = 0; mt < 2; ++mt)
      #pragma unroll
      for (int r = 0; r < 4; ++r) {
        float v = a2c[mt][r] + b2v;
        Gb[mt * 16 + lg * 4 + r][n1] = f2b(v > 0.f ? v : 0.f);
      }
    LGKM_BAR();  // b3: u_embed exchanged

    // gates: read A-frags first (regs), then barrier, then overwrite Gb
    bf16x8 ag[2][4];
    #pragma unroll
    for (int mt = 0; mt < 2; ++mt)
      #pragma unroll
      for (int kt = 0; kt < 4; ++kt)
        ag[mt][kt] = *reinterpret_cast<const bf16x8*>(&Gb[mt * 16 + lr][kt * 32 + lg * 8]);
    LGKM_BAR();  // b4: all u_embed reads done; Gb free for gate outputs

    #pragma unroll
    for (int j = 0; j < 3; ++j) {
      #pragma unroll
      for (int mt = 0; mt < 2; ++mt) {
        f32x4 c = {0.f, 0.f, 0.f, 0.f};
        #pragma unroll
        for (int kt = 0; kt < 4; ++kt)
          c = __builtin_amdgcn_mfma_f32_16x16x32_bf16(ag[mt][kt], wfg[j][kt], c, 0, 0, 0);
        #pragma unroll
        for (int r = 0; r < 4; ++r)
          Gb[mt * 16 + lg * 4 + r][w * 48 + j * 16 + lr] = f2b(c[r] + bgv[j]);
      }
    }
    LGKM_BAR();  // b5: gate tile assembled

    // vectorized readback + coalesced global store (row: 16 lanes x 48B)
    #pragma unroll
    for (int k = 0; k < 3; ++k) {
      bf16x8 vv = *reinterpret_cast<const bf16x8*>(&Gb[srow][gcol + k * 8]);
      *reinterpret_cast<bf16x8*>(gates + (m0 + srow) * 384 + gcol + k * 8) = vv;
    }
    // next tile's b1 drains these LDS reads before Gb is rewritten
  }
}

// ---------------------------------------------------------------------------
// K2: fused GRU scan + x-path (heterogeneous blocks).
// Blocks 0..63: GRU scan, 8 batch rows each (rows 8..15 of the MFMA tile are
// zero padding). After the hg MFMAs, v_permlane32_swap_b32 redistributes the
// valid rows so ALL 64 lanes own exactly 2 gru_h values (halves ew VALU).
// Blocks 64..575: x-path embedding on the otherwise-idle CUs.
// ---------------------------------------------------------------------------
__global__ __launch_bounds__(512) void k_grux(
    const short* __restrict__ gates, const short* __restrict__ whh,
    const float* __restrict__ bhh, float* __restrict__ hseq,
    const float* __restrict__ obs, const short* __restrict__ xw1,
    const float* __restrict__ xb1, const short* __restrict__ xw2,
    const float* __restrict__ xb2, float* __restrict__ xe)
{
  __shared__ short smem_[8 * 32 * 136];   // union: gru hb[2][16][136] | xpath 8x[32][136]
  const int tid = threadIdx.x, w = tid >> 6, l = tid & 63;
  const int lr = l & 15, lg = l >> 4;

  if (blockIdx.x < 64) {
    // ---------------- GRU path ----------------
    short (*hb)[16][136] = reinterpret_cast<short (*)[16][136]>(smem_);
    const int m0 = blockIdx.x * 8;
    const int c = w * 16 + lr;  // this lane's h/gate column (0..127)

    bf16x8 bfr[3][4];
    #pragma unroll
    for (int g = 0; g < 3; ++g)
      #pragma unroll
      for (int kt = 0; kt < 4; ++kt)
        bfr[g][kt] = *reinterpret_cast<const bf16x8*>(whh + (size_t)(g * 128 + c) * 128 + kt * 32 + lg * 8);
    const float bbn = bhh[256 + c];  // only n-gate bias survives (scaled by r)

    for (int i = tid; i < 2 * 16 * 136; i += 512) smem_[i] = 0;

    // lane's two owned rows after permlane redistribution:
    // lo lanes (lg<2): m = (lg&1)*4 + {0,1}; hi lanes: m = (lg&1)*4 + {2,3}
    const int mk0 = (lg & 1) * 4 + (lg >> 1) * 2;
    const int mk1 = mk0 + 1;
    const size_t gr0 = m0 + mk0, gr1 = m0 + mk1;   // global batch rows (0..511)

    float hold[2] = {0.f, 0.f};

    unsigned gA[3][2], gB[3][2];
    #pragma unroll
    for (int g = 0; g < 3; ++g) {
      gA[g][0] = (unsigned short)gates[gr0 * 384 + g * 128 + c];
      gA[g][1] = (unsigned short)gates[gr1 * 384 + g * 128 + c];
      gB[g][0] = (unsigned short)gates[(512 + gr0) * 384 + g * 128 + c];
      gB[g][1] = (unsigned short)gates[(512 + gr1) * 384 + g * 128 + c];
    }

    __syncthreads();

#define GRU_STEP(T, GC, BR, BW)                                                \
  {                                                                            \
    const int t_ = (T);                                                        \
    bf16x8 a_[4];                                                              \
    _Pragma("unroll")                                                          \
    for (int kt = 0; kt < 4; ++kt)                                             \
      a_[kt] = *reinterpret_cast<const bf16x8*>(&hb[BR][lr][kt * 32 + lg * 8]);\
    float e_[3][2];                                                            \
    _Pragma("unroll")                                                          \
    for (int g = 0; g < 3; ++g) {                                              \
      f32x4 cc = {0.f, 0.f, 0.f, 0.f};                                         \
      _Pragma("unroll")                                                        \
      for (int kt = 0; kt < 4; ++kt)                                           \
        cc = __builtin_amdgcn_mfma_f32_16x16x32_bf16(a_[kt], bfr[g][kt], cc, 0, 0, 0); \
      unsigned u0 = __float_as_uint(cc[0]), u2 = __float_as_uint(cc[2]);       \
      unsigned u1 = __float_as_uint(cc[1]), u3 = __float_as_uint(cc[3]);       \
      asm volatile("v_permlane32_swap_b32 %0, %1" : "+v"(u0), "+v"(u2));       \
      asm volatile("v_permlane32_swap_b32 %0, %1" : "+v"(u1), "+v"(u3));       \
      e_[g][0] = __uint_as_float(u0);                                          \
      e_[g][1] = __uint_as_float(u1);                                          \
    }                                                                          \
    _Pragma("unroll")                                                          \
    for (int k = 0; k < 2; ++k) {                                              \
      const int mk = k ? mk1 : mk0;                                            \
      const size_t grk = k ? gr1 : gr0;                                        \
      float rr = sigm(u2f(GC[0][k]) + e_[0][k]);                               \
      float zz = sigm(u2f(GC[1][k]) + e_[1][k]);                               \
      float tt = u2f(GC[2][k]) + (e_[2][k] + bbn) * rr;                        \
      float nn = 1.f - 2.f * rcpf(1.f + exp2f_(2.88539008f * tt));             \
      float ho = hold[k];                                                      \
      float hnew = nn + zz * (ho - nn);                                        \
      hseq[((size_t)t_ * 512 + grk) * 128 + c] = ho;                           \
      hold[k] = hnew;                                                          \
      hb[BW][mk][c] = f2b(hnew);                                               \
    }                                                                          \
    const int tp_ = (t_ + 2) & 255;                                            \
    _Pragma("unroll")                                                          \
    for (int g = 0; g < 3; ++g) {                                              \
      GC[g][0] = (unsigned short)gates[((size_t)tp_ * 512 + gr0) * 384 + g * 128 + c]; \
      GC[g][1] = (unsigned short)gates[((size_t)tp_ * 512 + gr1) * 384 + g * 128 + c]; \
    }                                                                          \
    asm volatile("s_waitcnt lgkmcnt(0)" ::: "memory");                         \
    __builtin_amdgcn_s_barrier();                                              \
    __builtin_amdgcn_sched_barrier(0);                                         \
  }

    for (int tt = 0; tt < 128; ++tt) {
      GRU_STEP(2 * tt,     gA, 0, 1)
      GRU_STEP(2 * tt + 1, gB, 1, 0)
    }
#undef GRU_STEP
  } else {
    // ---------------- x-path (obs -> relu fc -> relu fc = x_embed) ----------
    const int m0 = (blockIdx.x - 64) * 256 + w * 32;
    short (* __restrict__ B)[136] = reinterpret_cast<short (*)[136]>(&smem_[w * 32 * 136]);

    #pragma unroll
    for (int it = 0; it < 16; ++it) {
      int idx = (it * 64 + l) * 4;
      int row = idx >> 7, col = idx & 127;
      float4 v = *reinterpret_cast<const float4*>(obs + (size_t)(m0 + row) * 128 + col);
      bf16x4 p; p[0] = f2b(v.x); p[1] = f2b(v.y); p[2] = f2b(v.z); p[3] = f2b(v.w);
      *reinterpret_cast<bf16x4*>(&B[row][col]) = p;
    }

    f32x4 acc[2][8];
    bf16x8 a1f[2][4];
    #pragma unroll
    for (int mt = 0; mt < 2; ++mt)
      #pragma unroll
      for (int kt = 0; kt < 4; ++kt)
        a1f[mt][kt] = *reinterpret_cast<const bf16x8*>(&B[mt * 16 + lr][kt * 32 + lg * 8]);
    #pragma unroll
    for (int nt = 0; nt < 8; ++nt)
      #pragma unroll
      for (int mt = 0; mt < 2; ++mt) {
        f32x4 c = {0.f, 0.f, 0.f, 0.f};
        #pragma unroll
        for (int kt = 0; kt < 4; ++kt) {
          bf16x8 bv = *reinterpret_cast<const bf16x8*>(xw1 + (size_t)(nt * 16 + lr) * 128 + kt * 32 + lg * 8);
          c = __builtin_amdgcn_mfma_f32_16x16x32_bf16(a1f[mt][kt], bv, c, 0, 0, 0);
        }
        acc[mt][nt] = c;
      }
    #pragma unroll
    for (int nt = 0; nt < 8; ++nt) {
      float bb = xb1[nt * 16 + lr];
      #pragma unroll
      for (int mt = 0; mt < 2; ++mt)
        #pragma unroll
        for (int r = 0; r < 4; ++r) {
          float v = acc[mt][nt][r] + bb;
          B[mt * 16 + lg * 4 + r][nt * 16 + lr] = f2b(v > 0.f ? v : 0.f);
        }
    }

    bf16x8 a2f[2][4];
    #pragma unroll
    for (int mt = 0; mt < 2; ++mt)
      #pragma unroll
      for (int kt = 0; kt < 4; ++kt)
        a2f[mt][kt] = *reinterpret_cast<const bf16x8*>(&B[mt * 16 + lr][kt * 32 + lg * 8]);
    #pragma unroll
    for (int nt = 0; nt < 8; ++nt) {
      float bb = xb2[nt * 16 + lr];
      #pragma unroll
      for (int mt = 0; mt < 2; ++mt) {
        f32x4 c = {0.f, 0.f, 0.f, 0.f};
        #pragma unroll
        for (int kt = 0; kt < 4; ++kt) {
          bf16x8 bv = *reinterpret_cast<const bf16x8*>(xw2 + (size_t)(nt * 16 + lr) * 128 + kt * 32 + lg * 8);
          c = __builtin_amdgcn_mfma_f32_16x16x32_bf16(a2f[mt][kt], bv, c, 0, 0, 0);
        }
        #pragma unroll
        for (int r = 0; r < 4; ++r) {
          float v = c[r] + bb;
          xe[(size_t)(m0 + mt * 16 + lg * 4 + r) * 128 + nt * 16 + lr] = (v > 0.f ? v : 0.f);
        }
      }
    }
  }
}

// ---------------------------------------------------------------------------
// K4: posterior DBlock + reparam, v3. 512 blocks x 512 thr, grid-stride over
// 8 tiles of 32 rows. fc1 weight frags REGISTER-RESIDENT across tiles; fc2 and
// mu/ls frags re-streamed from L2 per tile (anti-LICM asm keeps them
// transient). A staged once in LDS; t overlays A. lgkm-only barriers.
// ---------------------------------------------------------------------------
#define PT 8
__global__ __launch_bounds__(512) void k_post(
    const float* __restrict__ xe, const float* __restrict__ hs, const float* __restrict__ eps,
    const short* __restrict__ pw1, const float* __restrict__ pb1,
    const short* __restrict__ pw2, const float* __restrict__ pb2,
    const short* __restrict__ pwmu, const float* __restrict__ pbmu,
    const short* __restrict__ pwls, const float* __restrict__ pbls,
    float* __restrict__ mu, float* __restrict__ ls, float* __restrict__ samp)
{
  __shared__ short Ab[32][264];
  const int tid = threadIdx.x, w = tid >> 6, l = tid & 63;
  const int lr = l & 15, lg = l >> 4;
  const int srow = tid >> 4, scol = (tid & 15) * 8;
  const int n2 = w * 16 + lr;           // ph2 output column (mu & ls)

  bf16x8 wf1[2][8];
  float bb1[2], bb2[2];
  #pragma unroll
  for (int j = 0; j < 2; ++j) {
    const int n = w * 32 + j * 16 + lr;
    bb1[j] = pb1[n]; bb2[j] = pb2[n];
    #pragma unroll
    for (int kt = 0; kt < 8; ++kt)
      wf1[j][kt] = *reinterpret_cast<const bf16x8*>(pw1 + (size_t)n * 256 + kt * 32 + lg * 8);
  }
  const float bbm = pbmu[n2], bbl = pbls[n2];

  for (int it = 0; it < PT; ++it) {
    const size_t m0 = ((size_t)blockIdx.x * PT + it) * 32;

    unsigned long long a2 = (unsigned long long)pw2;
    unsigned long long am_ = (unsigned long long)pwmu;
    unsigned long long al_ = (unsigned long long)pwls;
    asm volatile("" : "+s"(a2), "+s"(am_), "+s"(al_));
    const short* pw2v = (const short*)a2;
    const short* pwmv = (const short*)am_;
    const short* pwlv = (const short*)al_;

    float ev[2][4];
    #pragma unroll
    for (int mt = 0; mt < 2; ++mt)
      #pragma unroll
      for (int r = 0; r < 4; ++r)
        ev[mt][r] = eps[(m0 + mt * 16 + lg * 4 + r) * 128 + n2];

    {
      const float* px = xe + (m0 + srow) * 128 + scol;
      float4 v0 = *reinterpret_cast<const float4*>(px);
      float4 v1 = *reinterpret_cast<const float4*>(px + 4);
      bf16x8 pk;
      pk[0] = f2b(v0.x); pk[1] = f2b(v0.y); pk[2] = f2b(v0.z); pk[3] = f2b(v0.w);
      pk[4] = f2b(v1.x); pk[5] = f2b(v1.y); pk[6] = f2b(v1.z); pk[7] = f2b(v1.w);
      *reinterpret_cast<bf16x8*>(&Ab[srow][scol]) = pk;
      const float* ph = hs + (m0 + srow) * 128 + scol;
      float4 h0 = *reinterpret_cast<const float4*>(ph);
      float4 h1 = *reinterpret_cast<const float4*>(ph + 4);
      bf16x8 qk;
      qk[0] = f2b(h0.x); qk[1] = f2b(h0.y); qk[2] = f2b(h0.z); qk[3] = f2b(h0.w);
      qk[4] = f2b(h1.x); qk[5] = f2b(h1.y); qk[6] = f2b(h1.z); qk[7] = f2b(h1.w);
      *reinterpret_cast<bf16x8*>(&Ab[srow][128 + scol]) = qk;
    }
    LGKM_BAR();  // b1: A staged

    bf16x8 wf2[2][8];
    #pragma unroll
    for (int j = 0; j < 2; ++j) {
      const int n = w * 32 + j * 16 + lr;
      #pragma unroll
      for (int kt = 0; kt < 8; ++kt)
        wf2[j][kt] = *reinterpret_cast<const bf16x8*>(pw2v + (size_t)n * 256 + kt * 32 + lg * 8);
    }
    f32x4 ac1[2][2], ac2[2][2];
    #pragma unroll
    for (int j = 0; j < 2; ++j)
      #pragma unroll
      for (int mt = 0; mt < 2; ++mt) { ac1[j][mt] = (f32x4){0.f,0.f,0.f,0.f}; ac2[j][mt] = (f32x4){0.f,0.f,0.f,0.f}; }
    #pragma unroll
    for (int kt = 0; kt < 8; ++kt) {
      bf16x8 af[2];
      #pragma unroll
      for (int mt = 0; mt < 2; ++mt)
        af[mt] = *reinterpret_cast<const bf16x8*>(&Ab[mt * 16 + lr][kt * 32 + lg * 8]);
      #pragma unroll
      for (int j = 0; j < 2; ++j)
        #pragma unroll
        for (int mt = 0; mt < 2; ++mt) {
          ac1[j][mt] = __builtin_amdgcn_mfma_f32_16x16x32_bf16(af[mt], wf1[j][kt], ac1[j][mt], 0, 0, 0);
          ac2[j][mt] = __builtin_amdgcn_mfma_f32_16x16x32_bf16(af[mt], wf2[j][kt], ac2[j][mt], 0, 0, 0);
        }
    }

    bf16x8 wm[8], wl[8];
    #pragma unroll
    for (int kt = 0; kt < 8; ++kt) {
      wm[kt] = *reinterpret_cast<const bf16x8*>(pwmv + (size_t)n2 * 256 + kt * 32 + lg * 8);
      wl[kt] = *reinterpret_cast<const bf16x8*>(pwlv + (size_t)n2 * 256 + kt * 32 + lg * 8);
    }
    LGKM_BAR();  // b2: all A reads done; t may overlay

    #pragma unroll
    for (int j = 0; j < 2; ++j)
      #pragma unroll
      for (int mt = 0; mt < 2; ++mt)
        #pragma unroll
        for (int r = 0; r < 4; ++r) {
          float t1 = ac1[j][mt][r] + bb1[j]; t1 = t1 > 0.f ? t1 : 0.f;
          float t2 = sigm(ac2[j][mt][r] + bb2[j]);
          Ab[mt * 16 + lg * 4 + r][w * 32 + j * 16 + lr] = f2b(t1 * t2);
        }
    LGKM_BAR();  // b3: t ready

    f32x4 amc[2], alc[2];
    #pragma unroll
    for (int mt = 0; mt < 2; ++mt) { amc[mt] = (f32x4){0.f,0.f,0.f,0.f}; alc[mt] = (f32x4){0.f,0.f,0.f,0.f}; }
    #pragma unroll
    for (int kt = 0; kt < 8; ++kt) {
      bf16x8 at[2];
      #pragma unroll
      for (int mt = 0; mt < 2; ++mt)
        at[mt] = *reinterpret_cast<const bf16x8*>(&Ab[mt * 16 + lr][kt * 32 + lg * 8]);
      #pragma unroll
      for (int mt = 0; mt < 2; ++mt) {
        amc[mt] = __builtin_amdgcn_mfma_f32_16x16x32_bf16(at[mt], wm[kt], amc[mt], 0, 0, 0);
        alc[mt] = __builtin_amdgcn_mfma_f32_16x16x32_bf16(at[mt], wl[kt], alc[mt], 0, 0, 0);
      }
    }
    #pragma unroll
    for (int mt = 0; mt < 2; ++mt)
      #pragma unroll
      for (int r = 0; r < 4; ++r) {
        size_t off = (m0 + mt * 16 + lg * 4 + r) * 128 + n2;
        float m_ = amc[mt][r] + bbm;
        float l_ = alc[mt][r] + bbl;
        mu[off] = m_;
        ls[off] = l_;
        samp[off] = m_ + exp2f_(1.44269504f * l_) * ev[mt][r];
      }
    LGKM_BAR();  // b4: t consumed before next tile's stage overwrites
  }
}

// ---------------------------------------------------------------------------
extern "C" void kernel_launch(void* const* d_in, const int* in_sizes, int n_in,
                              void* d_out, int out_size, void* d_ws, size_t ws_size,
                              hipStream_t stream) {
  const float* ext   = (const float*)d_in[0];
  const float* obs   = (const float*)d_in[1];
  const float* eps   = (const float*)d_in[2];
  const float* u_w1  = (const float*)d_in[3];
  const float* u_b1  = (const float*)d_in[4];
  const float* u_w2  = (const float*)d_in[5];
  const float* u_b2  = (const float*)d_in[6];
  const float* x_w1  = (const float*)d_in[7];
  const float* x_b1  = (const float*)d_in[8];
  const float* x_w2  = (const float*)d_in[9];
  const float* x_b2  = (const float*)d_in[10];
  const float* pw1   = (const float*)d_in[11];
  const float* pb1   = (const float*)d_in[12];
  const float* pw2   = (const float*)d_in[13];
  const float* pb2   = (const float*)d_in[14];
  const float* pwmu  = (const float*)d_in[15];
  const float* pbmu  = (const float*)d_in[16];
  const float* pwls  = (const float*)d_in[17];
  const float* pbls  = (const float*)d_in[18];
  const float* g_wih = (const float*)d_in[19];
  const float* g_whh = (const float*)d_in[20];
  const float* g_bih = (const float*)d_in[21];
  const float* g_bhh = (const float*)d_in[22];

  float* out = (float*)d_out;
  float* o_mu = out;
  float* o_ls = out + 16777216;
  float* o_sp = out + 33554432;
  float* o_hs = out + 50331648;
  float* o_xe = out + 67108864;
  // bf16 x_gates scratch (L*B*384 shorts = 100 MB) lives at the start of the
  // output region; fully consumed by k_grux before k_post overwrites it.
  short* gates = (short*)out;

  short* wb = (short*)d_ws;
  short* c_uw1  = wb + 0;
  short* c_uw2  = wb + 8192;
  short* c_xw1  = wb + 24576;
  short* c_xw2  = wb + 40960;
  short* c_wih  = wb + 57344;
  short* c_whh  = wb + 106496;
  short* c_pw1  = wb + 155648;
  short* c_pw2  = wb + 221184;
  short* c_pwmu = wb + 286720;
  short* c_pwls = wb + 319488;

  k_cvt<<<1376, 256, 0, stream>>>(u_w1, u_w2, x_w1, x_w2, g_wih, g_whh,
                                  pw1, pw2, pwmu, pwls, wb);
  k_upath<<<512, 512, 0, stream>>>(ext, c_uw1, u_b1, c_uw2, u_b2, c_wih, g_bih, g_bhh, gates);
  k_grux<<<576, 512, 0, stream>>>(gates, c_whh, g_bhh, o_hs,
                                  obs, c_xw1, x_b1, c_xw2, x_b2, o_xe);
  k_post<<<512, 512, 0, stream>>>(o_xe, o_hs, eps, c_pw1, pb1, c_pw2, pb2,
                                  c_pwmu, pbmu, c_pwls, pbls, o_mu, o_ls, o_sp);
}

// Round 7
// 412.384 us; speedup vs baseline: 2.6252x; 1.0214x over previous
//
#include <hip/hip_runtime.h>

// ---------------------------------------------------------------------------
// VAERNN forward posterior, MI355X bf16-MFMA implementation.
// L=256 B=512 K=128 IN=64 STATE=128 OBS=128, LB = L*B = 131072 rows.
// ---------------------------------------------------------------------------

typedef __attribute__((ext_vector_type(8))) short bf16x8;
typedef __attribute__((ext_vector_type(4))) short bf16x4;
typedef __attribute__((ext_vector_type(4))) float f32x4;

#define LB 131072

__device__ __forceinline__ short f2b(float f) {
  union { float f; unsigned u; } v; v.f = f;
  unsigned r = (v.u + 0x7FFFu + ((v.u >> 16) & 1u)) >> 16;  // RNE
  return (short)r;
}
__device__ __forceinline__ float u2f(unsigned u) {
  union { unsigned u; float f; } v; v.u = u << 16; return v.f;
}
__device__ __forceinline__ float rcpf(float x) { return __builtin_amdgcn_rcpf(x); }
__device__ __forceinline__ float exp2f_(float x) { return __builtin_amdgcn_exp2f(x); }
__device__ __forceinline__ float sigm(float x) { return rcpf(1.f + exp2f_(-1.44269504f * x)); }

// lgkm-only barrier: LDS ordering without draining global loads/stores (T4).
#define LGKM_BAR()                                          \
  asm volatile("s_waitcnt lgkmcnt(0)" ::: "memory");        \
  __builtin_amdgcn_s_barrier();                             \
  __builtin_amdgcn_sched_barrier(0);

// ---------------------------------------------------------------------------
// K0: convert all weight matrices fp32 -> bf16 into workspace (contiguous).
// ---------------------------------------------------------------------------
__global__ __launch_bounds__(256) void k_cvt(
    const float* __restrict__ s0, const float* __restrict__ s1,
    const float* __restrict__ s2, const float* __restrict__ s3,
    const float* __restrict__ s4, const float* __restrict__ s5,
    const float* __restrict__ s6, const float* __restrict__ s7,
    const float* __restrict__ s8, const float* __restrict__ s9,
    short* __restrict__ dst)
{
  int i = blockIdx.x * 256 + threadIdx.x;
  if (i >= 352256) return;
  const float* src; int off;
  if      (i <   8192) { src = s0; off = i; }
  else if (i <  24576) { src = s1; off = i - 8192; }
  else if (i <  40960) { src = s2; off = i - 24576; }
  else if (i <  57344) { src = s3; off = i - 40960; }
  else if (i < 106496) { src = s4; off = i - 57344; }
  else if (i < 155648) { src = s5; off = i - 106496; }
  else if (i < 221184) { src = s6; off = i - 155648; }
  else if (i < 286720) { src = s7; off = i - 221184; }
  else if (i < 319488) { src = s8; off = i - 286720; }
  else                 { src = s9; off = i - 319488; }
  dst[i] = f2b(src[off]);
}

// ---------------------------------------------------------------------------
// K1: u-path v2: x(64) -> relu fc(128) -> relu fc(128) -> gates(384).
// 512 blocks x 512 thr, grid-stride 8 tiles of 32 rows. ALL weights
// register-resident. Gates written back through LDS for vectorized
// (48B/lane) coalesced global stores. lgkm-only barriers.
// ---------------------------------------------------------------------------
#define UT 8
__global__ __launch_bounds__(512) void k_upath(
    const float* __restrict__ x, const short* __restrict__ w1, const float* __restrict__ b1,
    const short* __restrict__ w2, const float* __restrict__ b2,
    const short* __restrict__ wih, const float* __restrict__ bih,
    const float* __restrict__ bhh,
    short* __restrict__ gates)
{
  __shared__ short Xb[32][72];
  __shared__ short Tb[32][136];
  __shared__ short Gb[32][392];
  const int tid = threadIdx.x, w = tid >> 6, l = tid & 63;
  const int lr = l & 15, lg = l >> 4;
  const int n1 = w * 16 + lr;   // this lane's layer1/layer2 output column

  bf16x8 wf1[2], wf2[4], wfg[3][4];
  #pragma unroll
  for (int kt = 0; kt < 2; ++kt)
    wf1[kt] = *reinterpret_cast<const bf16x8*>(w1 + (size_t)n1 * 64 + kt * 32 + lg * 8);
  #pragma unroll
  for (int kt = 0; kt < 4; ++kt)
    wf2[kt] = *reinterpret_cast<const bf16x8*>(w2 + (size_t)n1 * 128 + kt * 32 + lg * 8);
  float bgv[3];
  #pragma unroll
  for (int j = 0; j < 3; ++j) {
    const int cg = w * 48 + j * 16 + lr;
    bgv[j] = bih[cg] + (cg < 256 ? bhh[cg] : 0.f);  // fold bhh into r/z gates
    #pragma unroll
    for (int kt = 0; kt < 4; ++kt)
      wfg[j][kt] = *reinterpret_cast<const bf16x8*>(wih + (size_t)cg * 128 + kt * 32 + lg * 8);
  }
  const float b1v = b1[n1], b2v = b2[n1];
  const int srow = tid >> 4, scol4 = (tid & 15) * 4, gcol = (tid & 15) * 24;

  for (int it = 0; it < UT; ++it) {
    const size_t m0 = ((size_t)blockIdx.x * UT + it) * 32;

    // stage x (32 x 64) as bf16
    {
      float4 v = *reinterpret_cast<const float4*>(x + (m0 + srow) * 64 + scol4);
      bf16x4 p; p[0] = f2b(v.x); p[1] = f2b(v.y); p[2] = f2b(v.z); p[3] = f2b(v.w);
      *reinterpret_cast<bf16x4*>(&Xb[srow][scol4]) = p;
    }
    LGKM_BAR();  // b1: x staged (also drains prev tile's Gb readback reads)

    // layer1: K=64 -> 16 cols/wave
    f32x4 a1c[2] = {(f32x4){0.f,0.f,0.f,0.f}, (f32x4){0.f,0.f,0.f,0.f}};
    #pragma unroll
    for (int kt = 0; kt < 2; ++kt) {
      #pragma unroll
      for (int mt = 0; mt < 2; ++mt) {
        bf16x8 af = *reinterpret_cast<const bf16x8*>(&Xb[mt * 16 + lr][kt * 32 + lg * 8]);
        a1c[mt] = __builtin_amdgcn_mfma_f32_16x16x32_bf16(af, wf1[kt], a1c[mt], 0, 0, 0);
      }
    }
    #pragma unroll
    for (int mt = 0; mt < 2; ++mt)
      #pragma unroll
      for (int r = 0; r < 4; ++r) {
        float v = a1c[mt][r] + b1v;
        Tb[mt * 16 + lg * 4 + r][n1] = f2b(v > 0.f ? v : 0.f);
      }
    LGKM_BAR();  // b2: layer1 exchanged

    // layer2: K=128 -> 16 cols/wave; output exchanged via Gb[.][0..127]
    f32x4 a2c[2] = {(f32x4){0.f,0.f,0.f,0.f}, (f32x4){0.f,0.f,0.f,0.f}};
    #pragma unroll
    for (int kt = 0; kt < 4; ++kt) {
      #pragma unroll
      for (int mt = 0; mt < 2; ++mt) {
        bf16x8 af = *reinterpret_cast<const bf16x8*>(&Tb[mt * 16 + lr][kt * 32 + lg * 8]);
        a2c[mt] = __builtin_amdgcn_mfma_f32_16x16x32_bf16(af, wf2[kt], a2c[mt], 0, 0, 0);
      }
    }
    #pragma unroll
    for (int mt = 0; mt < 2; ++mt)
      #pragma unroll
      for (int r = 0; r < 4; ++r) {
        float v = a2c[mt][r] + b2v;
        Gb[mt * 16 + lg * 4 + r][n1] = f2b(v > 0.f ? v : 0.f);
      }
    LGKM_BAR();  // b3: u_embed exchanged

    // gates: read A-frags first (regs), then barrier, then overwrite Gb
    bf16x8 ag[2][4];
    #pragma unroll
    for (int mt = 0; mt < 2; ++mt)
      #pragma unroll
      for (int kt = 0; kt < 4; ++kt)
        ag[mt][kt] = *reinterpret_cast<const bf16x8*>(&Gb[mt * 16 + lr][kt * 32 + lg * 8]);
    LGKM_BAR();  // b4: all u_embed reads done; Gb free for gate outputs

    #pragma unroll
    for (int j = 0; j < 3; ++j) {
      #pragma unroll
      for (int mt = 0; mt < 2; ++mt) {
        f32x4 c = {0.f, 0.f, 0.f, 0.f};
        #pragma unroll
        for (int kt = 0; kt < 4; ++kt)
          c = __builtin_amdgcn_mfma_f32_16x16x32_bf16(ag[mt][kt], wfg[j][kt], c, 0, 0, 0);
        #pragma unroll
        for (int r = 0; r < 4; ++r)
          Gb[mt * 16 + lg * 4 + r][w * 48 + j * 16 + lr] = f2b(c[r] + bgv[j]);
      }
    }
    LGKM_BAR();  // b5: gate tile assembled

    // vectorized readback + coalesced global store (row: 16 lanes x 48B)
    #pragma unroll
    for (int k = 0; k < 3; ++k) {
      bf16x8 vv = *reinterpret_cast<const bf16x8*>(&Gb[srow][gcol + k * 8]);
      *reinterpret_cast<bf16x8*>(gates + (m0 + srow) * 384 + gcol + k * 8) = vv;
    }
    // next tile's b1 drains these LDS reads before Gb is rewritten
  }
}

// ---------------------------------------------------------------------------
// K2: fused GRU scan + x-path (heterogeneous blocks).
// Blocks 0..127: GRU scan, 4 batch rows each (rows 4..15 of the MFMA tile are
// zero). After hg MFMAs, v_permlane32_swap(c0,c2),(c1,c3) + v_permlane16_swap
// (c0,c1) gives EVERY lane exactly ONE gru_h value: (row=lg, col=lr-of-wave).
// Blocks 128..639: x-path embedding on the otherwise-idle CUs.
// ---------------------------------------------------------------------------
__global__ __launch_bounds__(512) void k_grux(
    const short* __restrict__ gates, const short* __restrict__ whh,
    const float* __restrict__ bhh, float* __restrict__ hseq,
    const float* __restrict__ obs, const short* __restrict__ xw1,
    const float* __restrict__ xb1, const short* __restrict__ xw2,
    const float* __restrict__ xb2, float* __restrict__ xe)
{
  __shared__ short smem_[8 * 32 * 136];   // union: gru hb[2][16][136] | xpath 8x[32][136]
  const int tid = threadIdx.x, w = tid >> 6, l = tid & 63;
  const int lr = l & 15, lg = l >> 4;

  if (blockIdx.x < 128) {
    // ---------------- GRU path ----------------
    short (*hb)[16][136] = reinterpret_cast<short (*)[16][136]>(smem_);
    const int m0 = blockIdx.x * 4;
    const int c = w * 16 + lr;   // this lane's h/gate column (0..127)
    const int row = lg;          // this lane's batch row within tile (0..3)
    const size_t gr = m0 + row;  // global batch row

    bf16x8 bfr[3][4];
    #pragma unroll
    for (int g = 0; g < 3; ++g)
      #pragma unroll
      for (int kt = 0; kt < 4; ++kt)
        bfr[g][kt] = *reinterpret_cast<const bf16x8*>(whh + (size_t)(g * 128 + c) * 128 + kt * 32 + lg * 8);
    const float bbn = bhh[256 + c];  // only n-gate bias survives (scaled by r)

    for (int i = tid; i < 2 * 16 * 136; i += 512) smem_[i] = 0;

    float hold = 0.f;

    unsigned gA[3], gB[3];
    #pragma unroll
    for (int g = 0; g < 3; ++g) {
      gA[g] = (unsigned short)gates[gr * 384 + g * 128 + c];
      gB[g] = (unsigned short)gates[(512 + gr) * 384 + g * 128 + c];
    }

    __syncthreads();

#define GRU_STEP(T, GC, BR, BW)                                                \
  {                                                                            \
    const int t_ = (T);                                                        \
    bf16x8 a_[4];                                                              \
    _Pragma("unroll")                                                          \
    for (int kt = 0; kt < 4; ++kt)                                             \
      a_[kt] = *reinterpret_cast<const bf16x8*>(&hb[BR][lr][kt * 32 + lg * 8]);\
    float e_[3];                                                               \
    _Pragma("unroll")                                                          \
    for (int g = 0; g < 3; ++g) {                                              \
      f32x4 cc = {0.f, 0.f, 0.f, 0.f};                                         \
      _Pragma("unroll")                                                        \
      for (int kt = 0; kt < 4; ++kt)                                           \
        cc = __builtin_amdgcn_mfma_f32_16x16x32_bf16(a_[kt], bfr[g][kt], cc, 0, 0, 0); \
    unsigned u0 = __float_as_uint(cc[0]), u2 = __float_as_uint(cc[2]);         \
    unsigned u1 = __float_as_uint(cc[1]), u3 = __float_as_uint(cc[3]);         \
    asm volatile("v_permlane32_swap_b32 %0, %1" : "+v"(u0), "+v"(u2));         \
    asm volatile("v_permlane32_swap_b32 %0, %1" : "+v"(u1), "+v"(u3));         \
    asm volatile("v_permlane16_swap_b32 %0, %1" : "+v"(u0), "+v"(u1));         \
      e_[g] = __uint_as_float(u0);                                             \
    }                                                                          \
    float rr = sigm(u2f(GC[0]) + e_[0]);                                       \
    float zz = sigm(u2f(GC[1]) + e_[1]);                                       \
    float tt = u2f(GC[2]) + (e_[2] + bbn) * rr;                                \
    float nn = 1.f - 2.f * rcpf(1.f + exp2f_(2.88539008f * tt));               \
    float hnew = nn + zz * (hold - nn);                                        \
    hseq[((size_t)t_ * 512 + gr) * 128 + c] = hold;                            \
    hold = hnew;                                                               \
    hb[BW][row][c] = f2b(hnew);                                                \
    const int tp_ = (t_ + 2) & 255;                                            \
    _Pragma("unroll")                                                          \
    for (int g = 0; g < 3; ++g)                                                \
      GC[g] = (unsigned short)gates[((size_t)tp_ * 512 + gr) * 384 + g * 128 + c]; \
    asm volatile("s_waitcnt lgkmcnt(0)" ::: "memory");                         \
    __builtin_amdgcn_s_barrier();                                              \
    __builtin_amdgcn_sched_barrier(0);                                         \
  }

    for (int tt = 0; tt < 128; ++tt) {
      GRU_STEP(2 * tt,     gA, 0, 1)
      GRU_STEP(2 * tt + 1, gB, 1, 0)
    }
#undef GRU_STEP
  } else {
    // ---------------- x-path (obs -> relu fc -> relu fc = x_embed) ----------
    const int m0 = (blockIdx.x - 128) * 256 + w * 32;
    short (* __restrict__ B)[136] = reinterpret_cast<short (*)[136]>(&smem_[w * 32 * 136]);

    #pragma unroll
    for (int it = 0; it < 16; ++it) {
      int idx = (it * 64 + l) * 4;
      int row = idx >> 7, col = idx & 127;
      float4 v = *reinterpret_cast<const float4*>(obs + (size_t)(m0 + row) * 128 + col);
      bf16x4 p; p[0] = f2b(v.x); p[1] = f2b(v.y); p[2] = f2b(v.z); p[3] = f2b(v.w);
      *reinterpret_cast<bf16x4*>(&B[row][col]) = p;
    }

    f32x4 acc[2][8];
    bf16x8 a1f[2][4];
    #pragma unroll
    for (int mt = 0; mt < 2; ++mt)
      #pragma unroll
      for (int kt = 0; kt < 4; ++kt)
        a1f[mt][kt] = *reinterpret_cast<const bf16x8*>(&B[mt * 16 + lr][kt * 32 + lg * 8]);
    #pragma unroll
    for (int nt = 0; nt < 8; ++nt)
      #pragma unroll
      for (int mt = 0; mt < 2; ++mt) {
        f32x4 c = {0.f, 0.f, 0.f, 0.f};
        #pragma unroll
        for (int kt = 0; kt < 4; ++kt) {
          bf16x8 bv = *reinterpret_cast<const bf16x8*>(xw1 + (size_t)(nt * 16 + lr) * 128 + kt * 32 + lg * 8);
          c = __builtin_amdgcn_mfma_f32_16x16x32_bf16(a1f[mt][kt], bv, c, 0, 0, 0);
        }
        acc[mt][nt] = c;
      }
    #pragma unroll
    for (int nt = 0; nt < 8; ++nt) {
      float bb = xb1[nt * 16 + lr];
      #pragma unroll
      for (int mt = 0; mt < 2; ++mt)
        #pragma unroll
        for (int r = 0; r < 4; ++r) {
          float v = acc[mt][nt][r] + bb;
          B[mt * 16 + lg * 4 + r][nt * 16 + lr] = f2b(v > 0.f ? v : 0.f);
        }
    }

    bf16x8 a2f[2][4];
    #pragma unroll
    for (int mt = 0; mt < 2; ++mt)
      #pragma unroll
      for (int kt = 0; kt < 4; ++kt)
        a2f[mt][kt] = *reinterpret_cast<const bf16x8*>(&B[mt * 16 + lr][kt * 32 + lg * 8]);
    #pragma unroll
    for (int nt = 0; nt < 8; ++nt) {
      float bb = xb2[nt * 16 + lr];
      #pragma unroll
      for (int mt = 0; mt < 2; ++mt) {
        f32x4 c = {0.f, 0.f, 0.f, 0.f};
        #pragma unroll
        for (int kt = 0; kt < 4; ++kt) {
          bf16x8 bv = *reinterpret_cast<const bf16x8*>(xw2 + (size_t)(nt * 16 + lr) * 128 + kt * 32 + lg * 8);
          c = __builtin_amdgcn_mfma_f32_16x16x32_bf16(a2f[mt][kt], bv, c, 0, 0, 0);
        }
        #pragma unroll
        for (int r = 0; r < 4; ++r) {
          float v = c[r] + bb;
          xe[(size_t)(m0 + mt * 16 + lg * 4 + r) * 128 + nt * 16 + lr] = (v > 0.f ? v : 0.f);
        }
      }
    }
  }
}

// ---------------------------------------------------------------------------
// K4: posterior DBlock + reparam, v3. 512 blocks x 512 thr, grid-stride over
// 8 tiles of 32 rows. fc1 weight frags REGISTER-RESIDENT across tiles; fc2 and
// mu/ls frags re-streamed from L2 per tile (anti-LICM asm keeps them
// transient). A staged once in LDS; t overlays A. lgkm-only barriers.
// ---------------------------------------------------------------------------
#define PT 8
__global__ __launch_bounds__(512) void k_post(
    const float* __restrict__ xe, const float* __restrict__ hs, const float* __restrict__ eps,
    const short* __restrict__ pw1, const float* __restrict__ pb1,
    const short* __restrict__ pw2, const float* __restrict__ pb2,
    const short* __restrict__ pwmu, const float* __restrict__ pbmu,
    const short* __restrict__ pwls, const float* __restrict__ pbls,
    float* __restrict__ mu, float* __restrict__ ls, float* __restrict__ samp)
{
  __shared__ short Ab[32][264];
  const int tid = threadIdx.x, w = tid >> 6, l = tid & 63;
  const int lr = l & 15, lg = l >> 4;
  const int srow = tid >> 4, scol = (tid & 15) * 8;
  const int n2 = w * 16 + lr;           // ph2 output column (mu & ls)

  bf16x8 wf1[2][8];
  float bb1[2], bb2[2];
  #pragma unroll
  for (int j = 0; j < 2; ++j) {
    const int n = w * 32 + j * 16 + lr;
    bb1[j] = pb1[n]; bb2[j] = pb2[n];
    #pragma unroll
    for (int kt = 0; kt < 8; ++kt)
      wf1[j][kt] = *reinterpret_cast<const bf16x8*>(pw1 + (size_t)n * 256 + kt * 32 + lg * 8);
  }
  const float bbm = pbmu[n2], bbl = pbls[n2];

  for (int it = 0; it < PT; ++it) {
    const size_t m0 = ((size_t)blockIdx.x * PT + it) * 32;

    unsigned long long a2 = (unsigned long long)pw2;
    unsigned long long am_ = (unsigned long long)pwmu;
    unsigned long long al_ = (unsigned long long)pwls;
    asm volatile("" : "+s"(a2), "+s"(am_), "+s"(al_));
    const short* pw2v = (const short*)a2;
    const short* pwmv = (const short*)am_;
    const short* pwlv = (const short*)al_;

    float ev[2][4];
    #pragma unroll
    for (int mt = 0; mt < 2; ++mt)
      #pragma unroll
      for (int r = 0; r < 4; ++r)
        ev[mt][r] = eps[(m0 + mt * 16 + lg * 4 + r) * 128 + n2];

    {
      const float* px = xe + (m0 + srow) * 128 + scol;
      float4 v0 = *reinterpret_cast<const float4*>(px);
      float4 v1 = *reinterpret_cast<const float4*>(px + 4);
      bf16x8 pk;
      pk[0] = f2b(v0.x); pk[1] = f2b(v0.y); pk[2] = f2b(v0.z); pk[3] = f2b(v0.w);
      pk[4] = f2b(v1.x); pk[5] = f2b(v1.y); pk[6] = f2b(v1.z); pk[7] = f2b(v1.w);
      *reinterpret_cast<bf16x8*>(&Ab[srow][scol]) = pk;
      const float* ph = hs + (m0 + srow) * 128 + scol;
      float4 h0 = *reinterpret_cast<const float4*>(ph);
      float4 h1 = *reinterpret_cast<const float4*>(ph + 4);
      bf16x8 qk;
      qk[0] = f2b(h0.x); qk[1] = f2b(h0.y); qk[2] = f2b(h0.z); qk[3] = f2b(h0.w);
      qk[4] = f2b(h1.x); qk[5] = f2b(h1.y); qk[6] = f2b(h1.z); qk[7] = f2b(h1.w);
      *reinterpret_cast<bf16x8*>(&Ab[srow][128 + scol]) = qk;
    }
    LGKM_BAR();  // b1: A staged

    bf16x8 wf2[2][8];
    #pragma unroll
    for (int j = 0; j < 2; ++j) {
      const int n = w * 32 + j * 16 + lr;
      #pragma unroll
      for (int kt = 0; kt < 8; ++kt)
        wf2[j][kt] = *reinterpret_cast<const bf16x8*>(pw2v + (size_t)n * 256 + kt * 32 + lg * 8);
    }
    f32x4 ac1[2][2], ac2[2][2];
    #pragma unroll
    for (int j = 0; j < 2; ++j)
      #pragma unroll
      for (int mt = 0; mt < 2; ++mt) { ac1[j][mt] = (f32x4){0.f,0.f,0.f,0.f}; ac2[j][mt] = (f32x4){0.f,0.f,0.f,0.f}; }
    #pragma unroll
    for (int kt = 0; kt < 8; ++kt) {
      bf16x8 af[2];
      #pragma unroll
      for (int mt = 0; mt < 2; ++mt)
        af[mt] = *reinterpret_cast<const bf16x8*>(&Ab[mt * 16 + lr][kt * 32 + lg * 8]);
      #pragma unroll
      for (int j = 0; j < 2; ++j)
        #pragma unroll
        for (int mt = 0; mt < 2; ++mt) {
          ac1[j][mt] = __builtin_amdgcn_mfma_f32_16x16x32_bf16(af[mt], wf1[j][kt], ac1[j][mt], 0, 0, 0);
          ac2[j][mt] = __builtin_amdgcn_mfma_f32_16x16x32_bf16(af[mt], wf2[j][kt], ac2[j][mt], 0, 0, 0);
        }
    }

    bf16x8 wm[8], wl[8];
    #pragma unroll
    for (int kt = 0; kt < 8; ++kt) {
      wm[kt] = *reinterpret_cast<const bf16x8*>(pwmv + (size_t)n2 * 256 + kt * 32 + lg * 8);
      wl[kt] = *reinterpret_cast<const bf16x8*>(pwlv + (size_t)n2 * 256 + kt * 32 + lg * 8);
    }
    LGKM_BAR();  // b2: all A reads done; t may overlay

    #pragma unroll
    for (int j = 0; j < 2; ++j)
      #pragma unroll
      for (int mt = 0; mt < 2; ++mt)
        #pragma unroll
        for (int r = 0; r < 4; ++r) {
          float t1 = ac1[j][mt][r] + bb1[j]; t1 = t1 > 0.f ? t1 : 0.f;
          float t2 = sigm(ac2[j][mt][r] + bb2[j]);
          Ab[mt * 16 + lg * 4 + r][w * 32 + j * 16 + lr] = f2b(t1 * t2);
        }
    LGKM_BAR();  // b3: t ready

    f32x4 amc[2], alc[2];
    #pragma unroll
    for (int mt = 0; mt < 2; ++mt) { amc[mt] = (f32x4){0.f,0.f,0.f,0.f}; alc[mt] = (f32x4){0.f,0.f,0.f,0.f}; }
    #pragma unroll
    for (int kt = 0; kt < 8; ++kt) {
      bf16x8 at[2];
      #pragma unroll
      for (int mt = 0; mt < 2; ++mt)
        at[mt] = *reinterpret_cast<const bf16x8*>(&Ab[mt * 16 + lr][kt * 32 + lg * 8]);
      #pragma unroll
      for (int mt = 0; mt < 2; ++mt) {
        amc[mt] = __builtin_amdgcn_mfma_f32_16x16x32_bf16(at[mt], wm[kt], amc[mt], 0, 0, 0);
        alc[mt] = __builtin_amdgcn_mfma_f32_16x16x32_bf16(at[mt], wl[kt], alc[mt], 0, 0, 0);
      }
    }
    #pragma unroll
    for (int mt = 0; mt < 2; ++mt)
      #pragma unroll
      for (int r = 0; r < 4; ++r) {
        size_t off = (m0 + mt * 16 + lg * 4 + r) * 128 + n2;
        float m_ = amc[mt][r] + bbm;
        float l_ = alc[mt][r] + bbl;
        mu[off] = m_;
        ls[off] = l_;
        samp[off] = m_ + exp2f_(1.44269504f * l_) * ev[mt][r];
      }
    LGKM_BAR();  // b4: t consumed before next tile's stage overwrites
  }
}

// ---------------------------------------------------------------------------
extern "C" void kernel_launch(void* const* d_in, const int* in_sizes, int n_in,
                              void* d_out, int out_size, void* d_ws, size_t ws_size,
                              hipStream_t stream) {
  const float* ext   = (const float*)d_in[0];
  const float* obs   = (const float*)d_in[1];
  const float* eps   = (const float*)d_in[2];
  const float* u_w1  = (const float*)d_in[3];
  const float* u_b1  = (const float*)d_in[4];
  const float* u_w2  = (const float*)d_in[5];
  const float* u_b2  = (const float*)d_in[6];
  const float* x_w1  = (const float*)d_in[7];
  const float* x_b1  = (const float*)d_in[8];
  const float* x_w2  = (const float*)d_in[9];
  const float* x_b2  = (const float*)d_in[10];
  const float* pw1   = (const float*)d_in[11];
  const float* pb1   = (const float*)d_in[12];
  const float* pw2   = (const float*)d_in[13];
  const float* pb2   = (const float*)d_in[14];
  const float* pwmu  = (const float*)d_in[15];
  const float* pbmu  = (const float*)d_in[16];
  const float* pwls  = (const float*)d_in[17];
  const float* pbls  = (const float*)d_in[18];
  const float* g_wih = (const float*)d_in[19];
  const float* g_whh = (const float*)d_in[20];
  const float* g_bih = (const float*)d_in[21];
  const float* g_bhh = (const float*)d_in[22];

  float* out = (float*)d_out;
  float* o_mu = out;
  float* o_ls = out + 16777216;
  float* o_sp = out + 33554432;
  float* o_hs = out + 50331648;
  float* o_xe = out + 67108864;
  // bf16 x_gates scratch (L*B*384 shorts = 100 MB) lives at the start of the
  // output region; fully consumed by k_grux before k_post overwrites it.
  short* gates = (short*)out;

  short* wb = (short*)d_ws;
  short* c_uw1  = wb + 0;
  short* c_uw2  = wb + 8192;
  short* c_xw1  = wb + 24576;
  short* c_xw2  = wb + 40960;
  short* c_wih  = wb + 57344;
  short* c_whh  = wb + 106496;
  short* c_pw1  = wb + 155648;
  short* c_pw2  = wb + 221184;
  short* c_pwmu = wb + 286720;
  short* c_pwls = wb + 319488;

  k_cvt<<<1376, 256, 0, stream>>>(u_w1, u_w2, x_w1, x_w2, g_wih, g_whh,
                                  pw1, pw2, pwmu, pwls, wb);
  k_upath<<<512, 512, 0, stream>>>(ext, c_uw1, u_b1, c_uw2, u_b2, c_wih, g_bih, g_bhh, gates);
  k_grux<<<640, 512, 0, stream>>>(gates, c_whh, g_bhh, o_hs,
                                  obs, c_xw1, x_b1, c_xw2, x_b2, o_xe);
  k_post<<<512, 512, 0, stream>>>(o_xe, o_hs, eps, c_pw1, pb1, c_pw2, pb2,
                                  c_pwmu, pbmu, c_pwls, pbls, o_mu, o_ls, o_sp);
}